// Round 8
// baseline (588.073 us; speedup 1.0000x reference)
//
#include <hip/hip_runtime.h>
#include <hip/hip_bf16.h>
#include <math.h>

typedef __bf16 bf16;
typedef __bf16 bf16x8 __attribute__((ext_vector_type(8)));
typedef __bf16 bf16x4 __attribute__((ext_vector_type(4)));
typedef float  f32x4  __attribute__((ext_vector_type(4)));
typedef short  s16x4  __attribute__((ext_vector_type(4)));

#define CLAMP(v) fminf(fmaxf((v), -100.f), 100.f)   // NaN tripwire; legit |v| <= ~40
#define NEGINF (-1e30f)

// native 2^x (v_exp_f32). __exp2f collides with glibc macros; use the amdgcn builtin.
static __device__ __forceinline__ float exp2fast(float x)
{
#if __has_builtin(__builtin_amdgcn_exp2f)
    return __builtin_amdgcn_exp2f(x);
#else
    return exp2f(x);
#endif
}

// K=16 bf16 MFMA (PV stage): builtin name differs across ROCm versions
static __device__ __forceinline__ f32x4 mfma16(bf16x4 a, bf16x4 b, f32x4 c)
{
#if __has_builtin(__builtin_amdgcn_mfma_f32_16x16x16_bf16)
    return __builtin_amdgcn_mfma_f32_16x16x16_bf16(a, b, c, 0, 0, 0);
#else
    s16x4 as, bs;
    __builtin_memcpy(&as, &a, 8);
    __builtin_memcpy(&bs, &b, 8);
    return __builtin_amdgcn_mfma_f32_16x16x16bf16_1k(as, bs, c, 0, 0, 0);
#endif
}

// async global -> LDS, 16B per lane. LDS dest is wave-uniform base + lane*16;
// global src is per-lane. (learn_hip m97 pattern)
static __device__ __forceinline__ void gload_lds16(const bf16* g, bf16* l)
{
    __builtin_amdgcn_global_load_lds(
        (const __attribute__((address_space(1))) void*)g,
        (__attribute__((address_space(3))) void*)l, 16, 0, 0);
}

// XCD-aware bijective block swizzle (T1, m157/m204): requires nwg % 8 == 0.
static __device__ __forceinline__ void xcd_swizzle(int& bx, int& by)
{
    int gx = gridDim.x, nwg = gx * gridDim.y;
    int lin = by * gx + bx;
    int cpx = nwg >> 3;
    int swz = (lin & 7) * cpx + (lin >> 3);
    bx = swz % gx;
    by = swz / gx;
}

// ---------------- 4x weight transpose + cast: dst_bf16[C][R] = src_f32[R][C], D x D ----------------
__global__ __launch_bounds__(256)
void transpose4_kernel(const float* __restrict__ Wq, const float* __restrict__ Wk,
                       const float* __restrict__ Wv, const float* __restrict__ Wo,
                       bf16* __restrict__ dstQKV, bf16* __restrict__ dstO)
{
    const int D = 1024;
    const float* src = (blockIdx.z == 0) ? Wq : (blockIdx.z == 1) ? Wk : (blockIdx.z == 2) ? Wv : Wo;
    bf16* dst = (blockIdx.z < 3) ? dstQKV + (size_t)blockIdx.z * D * D : dstO;
    __shared__ float tile[32][33];
    int c0 = blockIdx.x * 32, r0 = blockIdx.y * 32;
    int tx = threadIdx.x, ty = threadIdx.y;   // block (32,8)
#pragma unroll
    for (int i = 0; i < 4; i++)
        tile[ty + i * 8][tx] = src[(long)(r0 + ty + i * 8) * D + c0 + tx];
    __syncthreads();
#pragma unroll
    for (int i = 0; i < 4; i++)
        dst[(long)(c0 + ty + i * 8) * D + r0 + tx] = (bf16)tile[tx][ty + i * 8];
}

// ---------------- generic weight transpose + cast (W1/W2) ----------------
__global__ __launch_bounds__(256)
void transpose_kernel(const float* __restrict__ src, bf16* __restrict__ dst, int R, int C)
{
    __shared__ float tile[32][33];
    int c0 = blockIdx.x * 32, r0 = blockIdx.y * 32;
    int tx = threadIdx.x, ty = threadIdx.y;
#pragma unroll
    for (int i = 0; i < 4; i++)
        tile[ty + i * 8][tx] = src[(long)(r0 + ty + i * 8) * C + c0 + tx];
    __syncthreads();
#pragma unroll
    for (int i = 0; i < 4; i++)
        dst[(long)(c0 + ty + i * 8) * R + r0 + tx] = (bf16)tile[tx][ty + i * 8];
}

// ---------------- V transpose: Vt[bh][d][t] = qkv[(b*2048+t)*3072 + 2048 + h*64 + d] ----------------
__global__ __launch_bounds__(256)
void v_transpose(const bf16* __restrict__ qkv, bf16* __restrict__ Vt)
{
    __shared__ bf16 tile[32][33];
    int bh = blockIdx.z, b = bh >> 4, h = bh & 15;
    int t0 = blockIdx.x * 32, d0 = blockIdx.y * 32;
    int tx = threadIdx.x, ty = threadIdx.y;
#pragma unroll
    for (int i = 0; i < 4; i++)
        tile[ty + i * 8][tx] = qkv[(long)(b * 2048 + t0 + ty + i * 8) * 3072 + 2048 + h * 64 + d0 + tx];
    __syncthreads();
#pragma unroll
    for (int i = 0; i < 4; i++)
        Vt[((long)bh * 64 + d0 + ty + i * 8) * 2048 + t0 + tx] = tile[tx][ty + i * 8];
}

// ---------------- layernorm (row per block, D=1024, 256 thr), f32 in -> bf16 out ----------------
__global__ __launch_bounds__(256)
void ln_kernel(const float* __restrict__ x, const float* __restrict__ w, const float* __restrict__ b,
               bf16* __restrict__ out)
{
    const int D = 1024;
    const long row = blockIdx.x;
    const int t = threadIdx.x;
    f32x4 xv = *(const f32x4*)(x + row * D + t * 4);
    float s  = xv[0] + xv[1] + xv[2] + xv[3];
    float s2 = xv[0] * xv[0] + xv[1] * xv[1] + xv[2] * xv[2] + xv[3] * xv[3];
#pragma unroll
    for (int off = 32; off; off >>= 1) { s += __shfl_xor(s, off); s2 += __shfl_xor(s2, off); }
    __shared__ float ls[4], ls2[4];
    if ((t & 63) == 0) { ls[t >> 6] = s; ls2[t >> 6] = s2; }
    __syncthreads();
    s = ls[0] + ls[1] + ls[2] + ls[3];
    s2 = ls2[0] + ls2[1] + ls2[2] + ls2[3];
    float mu = s / D;
    float var = fmaxf(s2 / D - mu * mu, 0.f);
    float rstd = rsqrtf(var + 1e-5f);
#pragma unroll
    for (int i = 0; i < 4; i++) {
        int c = t * 4 + i;
        float v = (xv[i] - mu) * rstd * w[c] + b[c];
        out[row * D + c] = (bf16)CLAMP(v);
    }
}

// ---------------- GEMM 128x128 tile (Wo, FFN2), 2-phase double-buffered ----------------
// MODE 0: out bf16 = clamp(acc)                               (qkv)
// MODE 1: out bf16 = clamp(relu(acc + bias_f32[n]))           (FFN inner)
// MODE 2: out f32  = clamp(acc + resid_f32[m,n])              (x1 = ctx@Wo + x)
// MODE 3: out f32  = clamp(acc + bias_f32[n] + resid_f32[m,n])(final out)
// MODE 4: out f32 += clamp(acc)                               (k-split accumulate)
template <int MODE>
__global__ __launch_bounds__(256)
void gemm_bt(const bf16* __restrict__ A, int lda, const bf16* __restrict__ Bt, int ldb,
             int M, int N, int K,
             const float* __restrict__ bias, const float* __restrict__ resid,
             void* __restrict__ outv, int ldo)
{
    __shared__ bf16 sA[2][128 * 32];
    __shared__ bf16 sB[2][128 * 32];
    const int t = threadIdx.x;
    const int wave = t >> 6, lane = t & 63;
    const int wr = wave >> 1, wc = wave & 1;      // 2x2 wave grid, 64x64 per wave
    const int quad = lane >> 4, l16 = lane & 15;
    int bx = blockIdx.x, by = blockIdx.y;
    xcd_swizzle(bx, by);
    const int bm = by * 128, bn = bx * 128;

    f32x4 acc[4][4];
#pragma unroll
    for (int i = 0; i < 4; i++)
#pragma unroll
        for (int j = 0; j < 4; j++) acc[i][j] = f32x4{0.f, 0.f, 0.f, 0.f};

    const int srow = wave * 16 + (lane >> 2);     // global row within tile
    const int scol = (lane & 3) * 8;              // halfword col group (16B)
    const bf16* ga = A + (long)(bm + srow) * lda + scol;
    const bf16* gb = Bt + (long)(bn + srow) * ldb + scol;
    const int lbase = wave * 16 * 32;             // wave-uniform LDS base (halfwords)

#define STAGE128(buf, k0)                                                  \
    do {                                                                   \
        gload_lds16(ga + (k0), &sA[buf][lbase]);                           \
        gload_lds16(gb + (k0), &sB[buf][lbase]);                           \
        gload_lds16(ga + (long)64 * lda + (k0), &sA[buf][lbase + 64 * 32]);\
        gload_lds16(gb + (long)64 * ldb + (k0), &sB[buf][lbase + 64 * 32]);\
    } while (0)

    STAGE128(0, 0);
    __syncthreads();
    int cur = 0;
    for (int k0 = 0; k0 < K; k0 += 32) {
        if (k0 + 32 < K) STAGE128(cur ^ 1, k0 + 32);   // prefetch next tile
        bf16x8 af[4], bfv[4];
#pragma unroll
        for (int i = 0; i < 4; i++)
            af[i] = *(const bf16x8*)(&sA[cur][(wr * 64 + i * 16 + l16) * 32 + quad * 8]);
#pragma unroll
        for (int j = 0; j < 4; j++)
            bfv[j] = *(const bf16x8*)(&sB[cur][(wc * 64 + j * 16 + l16) * 32 + quad * 8]);
#pragma unroll
        for (int i = 0; i < 4; i++)
#pragma unroll
            for (int j = 0; j < 4; j++)
                acc[i][j] = __builtin_amdgcn_mfma_f32_16x16x32_bf16(af[i], bfv[j], acc[i][j], 0, 0, 0);
        __syncthreads();                               // drains prefetch vmcnt + read sync
        cur ^= 1;
    }
#undef STAGE128

    float bv[4];
    if constexpr (MODE == 1 || MODE == 3) {
#pragma unroll
        for (int j = 0; j < 4; j++) bv[j] = bias[bn + wc * 64 + j * 16 + l16];
    }
#pragma unroll
    for (int i = 0; i < 4; i++) {
        int m = bm + wr * 64 + i * 16 + quad * 4;
#pragma unroll
        for (int j = 0; j < 4; j++) {
            int n = bn + wc * 64 + j * 16 + l16;
#pragma unroll
            for (int r = 0; r < 4; r++) {
                float v = acc[i][j][r];
                long idx = (long)(m + r) * ldo + n;
                if constexpr (MODE == 0) {
                    ((bf16*)outv)[idx] = (bf16)CLAMP(v);
                } else if constexpr (MODE == 1) {
                    v += bv[j]; v = v > 0.f ? v : 0.f;
                    ((bf16*)outv)[idx] = (bf16)CLAMP(v);
                } else if constexpr (MODE == 2) {
                    ((float*)outv)[idx] = CLAMP(v + resid[idx]);
                } else if constexpr (MODE == 3) {
                    ((float*)outv)[idx] = CLAMP(v + bv[j] + resid[idx]);
                } else {   // MODE 4
                    ((float*)outv)[idx] += CLAMP(v);
                }
            }
        }
    }
}

// ---------------- GEMM 256x256 tile (QKV, FFN1), counted-vmcnt 2-deep pipeline (T4) ----------------
// r7 counters: MfmaUtil 22.5% — __syncthreads' vmcnt(0) drain exposes ~400cy/K-step of
// load latency (drains the same-iteration prefetch). Fix per m218: stage 2 tiles ahead,
// raw s_barrier + s_waitcnt vmcnt(4) (waits the OLDER tile only; newest 4 loads stay in
// flight across the barrier). vmcnt exact: loop contains no other VMEM ops.
// Schedule/K-step: {ds_read+MFMA buf[cur]; bar(reads done); STAGE(cur,k+2); vmcnt(4);
// bar(next buf ready)}. Tail drains vmcnt(0) once.
template <int MODE>
__global__ __launch_bounds__(512, 1)
void gemm256(const bf16* __restrict__ A, int lda, const bf16* __restrict__ Bt, int ldb,
             int M, int N, int K,
             const float* __restrict__ bias, const float* __restrict__ resid,
             void* __restrict__ outv, int ldo)
{
    __shared__ bf16 sA[2][256 * 32];
    __shared__ bf16 sB[2][256 * 32];
    const int t = threadIdx.x;
    const int wave = t >> 6, lane = t & 63;
    const int wr = wave >> 2, wc = wave & 3;      // 2x4 wave grid, 128x64 per wave
    const int quad = lane >> 4, l16 = lane & 15;
    int bx = blockIdx.x, by = blockIdx.y;
    xcd_swizzle(bx, by);
    const int bm = by * 256, bn = bx * 256;

    f32x4 acc[8][4];
#pragma unroll
    for (int i = 0; i < 8; i++)
#pragma unroll
        for (int j = 0; j < 4; j++) acc[i][j] = f32x4{0.f, 0.f, 0.f, 0.f};

    // staging: 512 threads cover 128 rows per call (row = t>>2, colgroup = (t&3)*8)
    const int srow = t >> 2;
    const int scol = (t & 3) * 8;
    const bf16* ga = A + (long)(bm + srow) * lda + scol;
    const bf16* gb = Bt + (long)(bn + srow) * ldb + scol;
    const int lbase = wave * 16 * 32;             // wave-uniform LDS base (lane*16B contiguous)

#define STAGE256(buf, k0)                                                    \
    do {                                                                     \
        gload_lds16(ga + (k0), &sA[buf][lbase]);                             \
        gload_lds16(gb + (k0), &sB[buf][lbase]);                             \
        gload_lds16(ga + (long)128 * lda + (k0), &sA[buf][lbase + 128 * 32]);\
        gload_lds16(gb + (long)128 * ldb + (k0), &sB[buf][lbase + 128 * 32]);\
    } while (0)

    STAGE256(0, 0);                                    // 4 loads in flight
    if (K > 32) STAGE256(1, 32);                       // 8 in flight
    asm volatile("s_waitcnt vmcnt(4)" ::: "memory");   // buf0 landed (oldest 4)
    __builtin_amdgcn_s_barrier();                      // all waves: buf0 ready
    int cur = 0;
    for (int k0 = 0; k0 < K; k0 += 32) {
        bf16x8 af[8], bfv[4];
#pragma unroll
        for (int i = 0; i < 8; i++)
            af[i] = *(const bf16x8*)(&sA[cur][(wr * 128 + i * 16 + l16) * 32 + quad * 8]);
#pragma unroll
        for (int j = 0; j < 4; j++)
            bfv[j] = *(const bf16x8*)(&sB[cur][(wc * 64 + j * 16 + l16) * 32 + quad * 8]);
#pragma unroll
        for (int i = 0; i < 8; i++)
#pragma unroll
            for (int j = 0; j < 4; j++)
                acc[i][j] = __builtin_amdgcn_mfma_f32_16x16x32_bf16(af[i], bfv[j], acc[i][j], 0, 0, 0);
        __builtin_amdgcn_s_barrier();                  // all waves done READING buf[cur]
        if (k0 + 64 < K) {
            STAGE256(cur, k0 + 64);                    // overwrite cur with tile k+2
            asm volatile("s_waitcnt vmcnt(4)" ::: "memory");  // older tile (next read) landed
        } else {
            asm volatile("s_waitcnt vmcnt(0)" ::: "memory");  // tail drain
        }
        __builtin_amdgcn_s_barrier();                  // all waves: next buf ready
        cur ^= 1;
    }
#undef STAGE256

    float bv[4];
    if constexpr (MODE == 1 || MODE == 3) {
#pragma unroll
        for (int j = 0; j < 4; j++) bv[j] = bias[bn + wc * 64 + j * 16 + l16];
    }
#pragma unroll
    for (int i = 0; i < 8; i++) {
        int m = bm + wr * 128 + i * 16 + quad * 4;
#pragma unroll
        for (int j = 0; j < 4; j++) {
            int n = bn + wc * 64 + j * 16 + l16;
#pragma unroll
            for (int r = 0; r < 4; r++) {
                float v = acc[i][j][r];
                long idx = (long)(m + r) * ldo + n;
                if constexpr (MODE == 0) {
                    ((bf16*)outv)[idx] = (bf16)CLAMP(v);
                } else if constexpr (MODE == 1) {
                    v += bv[j]; v = v > 0.f ? v : 0.f;
                    ((bf16*)outv)[idx] = (bf16)CLAMP(v);
                } else if constexpr (MODE == 2) {
                    ((float*)outv)[idx] = CLAMP(v + resid[idx]);
                } else if constexpr (MODE == 3) {
                    ((float*)outv)[idx] = CLAMP(v + bv[j] + resid[idx]);
                } else {   // MODE 4
                    ((float*)outv)[idx] += CLAMP(v);
                }
            }
        }
    }
}

// ---------------- MFMA causal flash attention, S^T formulation, DIAGONAL-PAIRED ----------------
#define SM_C 0.1803368801111f   // 0.125 * log2(e)

static __device__ __forceinline__ void attn_tile(
    const bf16x8 kf[4][2], const bf16* sVt, int t0, int qpb,
    int quad, int l16,
    const bf16x8 qf[2][2], f32x4 o[2][4], float* m_i, float* l_i)
{
    if (t0 > qpb + 31) return;    // whole wave-tile causally masked
    bf16x4 pb[2][4];
#pragma unroll
    for (int rf = 0; rf < 2; rf++) {
        f32x4 sc[4];
#pragma unroll
        for (int tt = 0; tt < 4; tt++) {
            f32x4 s4 = f32x4{0.f, 0.f, 0.f, 0.f};
            s4 = __builtin_amdgcn_mfma_f32_16x16x32_bf16(kf[tt][0], qf[rf][0], s4, 0, 0, 0);
            s4 = __builtin_amdgcn_mfma_f32_16x16x32_bf16(kf[tt][1], qf[rf][1], s4, 0, 0, 0);
            sc[tt] = s4;
        }
        const int qpos = qpb + rf * 16 + l16;
        if (t0 + 63 > qpb + rf * 16) {            // boundary tile: mask (wave-uniform branch)
#pragma unroll
            for (int tt = 0; tt < 4; tt++)
#pragma unroll
                for (int r = 0; r < 4; r++) {
                    int tcol = t0 + tt * 16 + quad * 4 + r;
                    float v = sc[tt][r] * SM_C;
                    sc[tt][r] = (tcol > qpos) ? NEGINF : v;
                }
        } else {                                   // interior tile: no mask VALU
#pragma unroll
            for (int tt = 0; tt < 4; tt++)
#pragma unroll
                for (int r = 0; r < 4; r++) sc[tt][r] = sc[tt][r] * SM_C;
        }
        float t4[4];
#pragma unroll
        for (int tt = 0; tt < 4; tt++)
            t4[tt] = fmaxf(fmaxf(sc[tt][0], sc[tt][1]), fmaxf(sc[tt][2], sc[tt][3]));
        float mt = fmaxf(fmaxf(t4[0], t4[1]), fmaxf(t4[2], t4[3]));
        mt = fmaxf(mt, __shfl_xor(mt, 16));
        mt = fmaxf(mt, __shfl_xor(mt, 32));
        float mn = fmaxf(m_i[rf], mt);
        float alpha = exp2fast(m_i[rf] - mn);
        m_i[rf] = mn;
        float lt4[4];
#pragma unroll
        for (int tt = 0; tt < 4; tt++) {
            float e0 = exp2fast(sc[tt][0] - mn);
            float e1 = exp2fast(sc[tt][1] - mn);
            float e2 = exp2fast(sc[tt][2] - mn);
            float e3 = exp2fast(sc[tt][3] - mn);
            sc[tt][0] = e0; sc[tt][1] = e1; sc[tt][2] = e2; sc[tt][3] = e3;
            lt4[tt] = (e0 + e1) + (e2 + e3);
        }
        float lt = (lt4[0] + lt4[1]) + (lt4[2] + lt4[3]);
        lt += __shfl_xor(lt, 16);
        lt += __shfl_xor(lt, 32);
        l_i[rf] = l_i[rf] * alpha + lt;
#pragma unroll
        for (int jb = 0; jb < 4; jb++)
#pragma unroll
            for (int r = 0; r < 4; r++) o[rf][jb][r] *= alpha;
#pragma unroll
        for (int tt = 0; tt < 4; tt++)
            pb[rf][tt] = bf16x4{(bf16)sc[tt][0], (bf16)sc[tt][1], (bf16)sc[tt][2], (bf16)sc[tt][3]};
    }
    // PV: O^T += V^T . P^T  (16x16x16, K-accumulate over tt)
#pragma unroll
    for (int jb = 0; jb < 4; jb++) {
#pragma unroll
        for (int tt = 0; tt < 4; tt++) {
            bf16x4 va = *(const bf16x4*)(&sVt[(jb * 16 + l16) * 72 + tt * 16 + quad * 4]);
            o[0][jb] = mfma16(va, pb[0][tt], o[0][jb]);
            o[1][jb] = mfma16(va, pb[1][tt], o[1][jb]);
        }
    }
}

__global__ __launch_bounds__(256, 2)
void attn_kernel(const bf16* __restrict__ qkv, const bf16* __restrict__ Vt, bf16* __restrict__ ctx)
{
    const int bh = blockIdx.x;
    const int p  = blockIdx.y;            // diagonal pair 0..7
    const int b = bh >> 4, h = bh & 15;
    const int t = threadIdx.x;
    const int wave = t >> 6, lane = t & 63;
    const int quad = lane >> 4, l16 = lane & 15;
    const long RS = 3072;
    const int qb0 = p, qb1 = 15 - p;
    const int nt0 = 2 * p + 2, nt1 = 32 - 2 * p;

    __shared__ bf16 sK[64 * 72];      // [t][d]
    __shared__ bf16 sVt[64 * 72];     // [d][t]

    bf16x8 qf[2][2][2];
#pragma unroll
    for (int s = 0; s < 2; s++) {
        const int qb = s ? qb1 : qb0;
#pragma unroll
        for (int rf = 0; rf < 2; rf++) {
            const bf16* qp = qkv + (long)(b * 2048 + qb * 128 + wave * 32 + rf * 16 + l16) * RS + h * 64 + quad * 8;
            qf[s][rf][0] = *(const bf16x8*)(qp);
            qf[s][rf][1] = *(const bf16x8*)(qp + 32);
        }
    }
    f32x4 o[2][2][4];                  // [s][rf][jb]
#pragma unroll
    for (int s = 0; s < 2; s++)
#pragma unroll
        for (int rf = 0; rf < 2; rf++)
#pragma unroll
            for (int jb = 0; jb < 4; jb++) o[s][rf][jb] = f32x4{0.f, 0.f, 0.f, 0.f};
    float m_i[2][2] = {{NEGINF, NEGINF}, {NEGINF, NEGINF}};
    float l_i[2][2] = {{0.f, 0.f}, {0.f, 0.f}};
    const int qpb0 = qb0 * 128 + wave * 32;
    const int qpb1 = qb1 * 128 + wave * 32;

    const int cg = (t & 7) * 8, rr = t >> 3;
    const bf16* Kbase  = qkv + (long)(b * 2048) * RS + 1024 + h * 64;
    const bf16* Vtbase = Vt + ((long)bh * 64) * 2048;

    bf16x8 kreg[2], vreg[2];
#pragma unroll
    for (int pp = 0; pp < 2; pp++) {   // prefetch tile 0
        kreg[pp] = *(const bf16x8*)(Kbase + (long)(pp * 32 + rr) * RS + cg);
        vreg[pp] = *(const bf16x8*)(Vtbase + (long)(pp * 32 + rr) * 2048 + cg);
    }

    for (int ti = 0; ti < nt1; ti++) {
        __syncthreads();
#pragma unroll
        for (int pp = 0; pp < 2; pp++) {
            *(bf16x8*)(&sK[(pp * 32 + rr) * 72 + cg]) = kreg[pp];
            *(bf16x8*)(&sVt[(pp * 32 + rr) * 72 + cg]) = vreg[pp];
        }
        __syncthreads();
        if (ti + 1 < nt1) {
            int t0n = (ti + 1) * 64;
#pragma unroll
            for (int pp = 0; pp < 2; pp++) {
                kreg[pp] = *(const bf16x8*)(Kbase + (long)(t0n + pp * 32 + rr) * RS + cg);
                vreg[pp] = *(const bf16x8*)(Vtbase + (long)(pp * 32 + rr) * 2048 + t0n + cg);
            }
        }
        const int t0 = ti * 64;

        bf16x8 kf[4][2];
#pragma unroll
        for (int tt = 0; tt < 4; tt++) {
            kf[tt][0] = *(const bf16x8*)(&sK[(tt * 16 + l16) * 72 + quad * 8]);
            kf[tt][1] = *(const bf16x8*)(&sK[(tt * 16 + l16) * 72 + 32 + quad * 8]);
        }
        if (ti < nt0)
            attn_tile(kf, sVt, t0, qpb0, quad, l16, qf[0], o[0], m_i[0], l_i[0]);
        attn_tile(kf, sVt, t0, qpb1, quad, l16, qf[1], o[1], m_i[1], l_i[1]);
    }
#pragma unroll
    for (int s = 0; s < 2; s++) {
        const int qpb = s ? qpb1 : qpb0;
#pragma unroll
        for (int rf = 0; rf < 2; rf++) {
            float rl = 1.0f / l_i[s][rf];
            const long row = (long)(b * 2048 + qpb + rf * 16 + l16) * 1024 + h * 64;
#pragma unroll
            for (int jb = 0; jb < 4; jb++) {
                bf16x4 ov;
#pragma unroll
                for (int r = 0; r < 4; r++) ov[r] = (bf16)CLAMP(o[s][rf][jb][r] * rl);
                *(bf16x4*)(&ctx[row + jb * 16 + quad * 4]) = ov;
            }
        }
    }
}

// ---------------- confidence head (f32) ----------------
__global__ __launch_bounds__(256)
void conf_partial(const float* __restrict__ xout, const float* __restrict__ cw, float* __restrict__ part)
{
    int blk = blockIdx.x;
    int b = blk >> 6, chunk = blk & 63;
    int t = threadIdx.x;
    int d0 = t * 4;
    f32x4 w = *(const f32x4*)(cw + d0);
    float acc = 0.f;
    for (int s = chunk * 32; s < chunk * 32 + 32; s++) {
        f32x4 v = *(const f32x4*)(xout + (long)(b * 2048 + s) * 1024 + d0);
        acc += v[0] * w[0] + v[1] * w[1] + v[2] * w[2] + v[3] * w[3];
    }
#pragma unroll
    for (int off = 32; off; off >>= 1) acc += __shfl_xor(acc, off);
    __shared__ float ls[4];
    if ((t & 63) == 0) ls[t >> 6] = acc;
    __syncthreads();
    if (t == 0) part[blk] = ls[0] + ls[1] + ls[2] + ls[3];
}

__global__ void conf_final(const float* __restrict__ part, const float* __restrict__ cb, float* __restrict__ outp)
{
    if (threadIdx.x == 0) {
        float accb = 0.f;
        for (int b = 0; b < 4; b++) {
            float s = 0.f;
            for (int i = 0; i < 64; i++) s += part[b * 64 + i];
            float z = s / 2048.0f + cb[0];
            accb += 1.0f / (1.0f + expf(-z));
        }
        outp[0] = accb * 0.25f;
    }
}

// ---------------- launch ----------------
// Workspace (1 MB = 1<<20), peak 96 MB + 1 KB, phase-disjoint aliasing:
//  [ 0, 8): WqkvT (ph1-3) -> W1T (ph6+)
//  [ 8,16): WoT (ph1-5)   -> W2T (ph6+)
//  [16,32): h (ph2-3) -> ctx (ph4-5) -> h2 (ph7-9)
//  [32,80): qkv (ph3-4); x1 f32 [32,64) ph5+ (qkv dead)
//  [80,96): Vt (ph3.5-4); a1h [64,96) ph8-9 (qkv tail + Vt dead)
//  [96MB):  part f32[256]
extern "C" void kernel_launch(void* const* d_in, const int* in_sizes, int n_in,
                              void* d_out, int out_size, void* d_ws, size_t ws_size,
                              hipStream_t stream)
{
    const int D = 1024, F = 4096, M = 8192;
    const size_t MB = 1u << 20;
    const float* x     = (const float*)d_in[0];
    const float* Wq    = (const float*)d_in[1];
    const float* Wk    = (const float*)d_in[2];
    const float* Wv    = (const float*)d_in[3];
    const float* Wo    = (const float*)d_in[4];
    const float* ln1w  = (const float*)d_in[5];
    const float* ln1b  = (const float*)d_in[6];
    const float* W1    = (const float*)d_in[7];
    const float* b1    = (const float*)d_in[8];
    const float* W2    = (const float*)d_in[9];
    const float* b2    = (const float*)d_in[10];
    const float* ln2w  = (const float*)d_in[11];
    const float* ln2b  = (const float*)d_in[12];
    const float* confw = (const float*)d_in[13];
    const float* confb = (const float*)d_in[14];
    float* out = (float*)d_out;

    char* ws = (char*)d_ws;
    bf16*  WqkvT = (bf16*)(ws);
    bf16*  WoT   = (bf16*)(ws + 8 * MB);
    bf16*  h     = (bf16*)(ws + 16 * MB);
    bf16*  qkv   = (bf16*)(ws + 32 * MB);
    bf16*  Vt    = (bf16*)(ws + 80 * MB);
    bf16*  ctx   = (bf16*)(ws + 16 * MB);
    float* x1    = (float*)(ws + 32 * MB);
    bf16*  h2    = (bf16*)(ws + 16 * MB);
    bf16*  W1T   = (bf16*)(ws);
    bf16*  W2T   = (bf16*)(ws + 8 * MB);
    bf16*  a1h   = (bf16*)(ws + 64 * MB);
    float* part  = (float*)(ws + 96 * MB);

    dim3 tb(32, 8);
    // ph1: QKV/Wo weight transposes in one launch
    transpose4_kernel<<<dim3(32, 32, 4), tb, 0, stream>>>(Wq, Wk, Wv, Wo, WqkvT, WoT);
    // ph2: LN1
    ln_kernel<<<M, 256, 0, stream>>>(x, ln1w, ln1b, h);
    // ph3: QKV projection (256^2 tile: 384 blocks)
    gemm256<0><<<dim3(12, 32), 512, 0, stream>>>(h, D, WqkvT, D, M, 3 * D, D, nullptr, nullptr, qkv, 3 * D);
    // ph3.5: V transpose
    v_transpose<<<dim3(64, 2, 64), tb, 0, stream>>>(qkv, Vt);
    // ph4: attention (diagonal-paired: 512 uniform blocks, fully co-resident)
    attn_kernel<<<dim3(64, 8), 256, 0, stream>>>(qkv, Vt, ctx);
    // ph5: Wo projection + residual -> x1 f32 (128^2: 512 blocks)
    gemm_bt<2><<<dim3(8, 64), 256, 0, stream>>>(ctx, D, WoT, D, M, D, D, nullptr, x, x1, D);
    // ph6: FFN weight transposes
    transpose_kernel<<<dim3(F / 32, D / 32), tb, 0, stream>>>(W1, W1T, D, F);
    transpose_kernel<<<dim3(D / 32, F / 32), tb, 0, stream>>>(W2, W2T, F, D);
    // ph7: LN2
    ln_kernel<<<M, 256, 0, stream>>>(x1, ln2w, ln2b, h2);
    // ph8: FFN half 1 (inner 256^2: 256 blocks; outer 128^2 k-split accumulate)
    gemm256<1><<<dim3(8, 32), 512, 0, stream>>>(h2, D, W1T, D, M, 2048, D, b1, nullptr, a1h, 2048);
    gemm_bt<4><<<dim3(8, 64), 256, 0, stream>>>(a1h, 2048, W2T, F, M, D, 2048, nullptr, nullptr, x1, D);
    // ph9: FFN half 2 -> out f32
    gemm256<1><<<dim3(8, 32), 512, 0, stream>>>(h2, D, W1T + (size_t)2048 * D, D, M, 2048, D, b1 + 2048, nullptr, a1h, 2048);
    gemm_bt<3><<<dim3(8, 64), 256, 0, stream>>>(a1h, 2048, W2T + 2048, F, M, D, 2048, b2, x1, out, D);
    // ph10: confidence head
    conf_partial<<<256, 256, 0, stream>>>(out, confw, part);
    conf_final<<<1, 64, 0, stream>>>(part, confb, out + (size_t)M * D);
}

// Round 9
// 554.540 us; speedup vs baseline: 1.0605x; 1.0605x over previous
//
#include <hip/hip_runtime.h>
#include <hip/hip_bf16.h>
#include <math.h>

typedef __bf16 bf16;
typedef __bf16 bf16x8 __attribute__((ext_vector_type(8)));
typedef __bf16 bf16x4 __attribute__((ext_vector_type(4)));
typedef float  f32x4  __attribute__((ext_vector_type(4)));
typedef short  s16x4  __attribute__((ext_vector_type(4)));

#define CLAMP(v) fminf(fmaxf((v), -100.f), 100.f)   // NaN tripwire; legit |v| <= ~40
#define NEGINF (-1e30f)

// native 2^x (v_exp_f32). __exp2f collides with glibc macros; use the amdgcn builtin.
static __device__ __forceinline__ float exp2fast(float x)
{
#if __has_builtin(__builtin_amdgcn_exp2f)
    return __builtin_amdgcn_exp2f(x);
#else
    return exp2f(x);
#endif
}

// K=16 bf16 MFMA (PV stage): builtin name differs across ROCm versions
static __device__ __forceinline__ f32x4 mfma16(bf16x4 a, bf16x4 b, f32x4 c)
{
#if __has_builtin(__builtin_amdgcn_mfma_f32_16x16x16_bf16)
    return __builtin_amdgcn_mfma_f32_16x16x16_bf16(a, b, c, 0, 0, 0);
#else
    s16x4 as, bs;
    __builtin_memcpy(&as, &a, 8);
    __builtin_memcpy(&bs, &b, 8);
    return __builtin_amdgcn_mfma_f32_16x16x16bf16_1k(as, bs, c, 0, 0, 0);
#endif
}

// async global -> LDS, 16B per lane. LDS dest is wave-uniform base + lane*16;
// global src is per-lane. (learn_hip m97 pattern)
static __device__ __forceinline__ void gload_lds16(const bf16* g, bf16* l)
{
    __builtin_amdgcn_global_load_lds(
        (const __attribute__((address_space(1))) void*)g,
        (__attribute__((address_space(3))) void*)l, 16, 0, 0);
}

// XCD-aware bijective block swizzle (T1, m157/m204): requires nwg % 8 == 0.
static __device__ __forceinline__ void xcd_swizzle(int& bx, int& by)
{
    int gx = gridDim.x, nwg = gx * gridDim.y;
    int lin = by * gx + bx;
    int cpx = nwg >> 3;
    int swz = (lin & 7) * cpx + (lin >> 3);
    bx = swz % gx;
    by = swz / gx;
}

// ---------------- 4x weight transpose + cast: dst_bf16[C][R] = src_f32[R][C], D x D ----------------
__global__ __launch_bounds__(256)
void transpose4_kernel(const float* __restrict__ Wq, const float* __restrict__ Wk,
                       const float* __restrict__ Wv, const float* __restrict__ Wo,
                       bf16* __restrict__ dstQKV, bf16* __restrict__ dstO)
{
    const int D = 1024;
    const float* src = (blockIdx.z == 0) ? Wq : (blockIdx.z == 1) ? Wk : (blockIdx.z == 2) ? Wv : Wo;
    bf16* dst = (blockIdx.z < 3) ? dstQKV + (size_t)blockIdx.z * D * D : dstO;
    __shared__ float tile[32][33];
    int c0 = blockIdx.x * 32, r0 = blockIdx.y * 32;
    int tx = threadIdx.x, ty = threadIdx.y;   // block (32,8)
#pragma unroll
    for (int i = 0; i < 4; i++)
        tile[ty + i * 8][tx] = src[(long)(r0 + ty + i * 8) * D + c0 + tx];
    __syncthreads();
#pragma unroll
    for (int i = 0; i < 4; i++)
        dst[(long)(c0 + ty + i * 8) * D + r0 + tx] = (bf16)tile[tx][ty + i * 8];
}

// ---------------- generic weight transpose + cast (W1/W2) ----------------
__global__ __launch_bounds__(256)
void transpose_kernel(const float* __restrict__ src, bf16* __restrict__ dst, int R, int C)
{
    __shared__ float tile[32][33];
    int c0 = blockIdx.x * 32, r0 = blockIdx.y * 32;
    int tx = threadIdx.x, ty = threadIdx.y;
#pragma unroll
    for (int i = 0; i < 4; i++)
        tile[ty + i * 8][tx] = src[(long)(r0 + ty + i * 8) * C + c0 + tx];
    __syncthreads();
#pragma unroll
    for (int i = 0; i < 4; i++)
        dst[(long)(c0 + ty + i * 8) * R + r0 + tx] = (bf16)tile[tx][ty + i * 8];
}

// ---------------- V transpose: Vt[bh][d][t] = qkv[(b*2048+t)*3072 + 2048 + h*64 + d] ----------------
__global__ __launch_bounds__(256)
void v_transpose(const bf16* __restrict__ qkv, bf16* __restrict__ Vt)
{
    __shared__ bf16 tile[32][33];
    int bh = blockIdx.z, b = bh >> 4, h = bh & 15;
    int t0 = blockIdx.x * 32, d0 = blockIdx.y * 32;
    int tx = threadIdx.x, ty = threadIdx.y;
#pragma unroll
    for (int i = 0; i < 4; i++)
        tile[ty + i * 8][tx] = qkv[(long)(b * 2048 + t0 + ty + i * 8) * 3072 + 2048 + h * 64 + d0 + tx];
    __syncthreads();
#pragma unroll
    for (int i = 0; i < 4; i++)
        Vt[((long)bh * 64 + d0 + ty + i * 8) * 2048 + t0 + tx] = tile[tx][ty + i * 8];
}

// ---------------- layernorm (row per block, D=1024, 256 thr), f32 in -> bf16 out ----------------
__global__ __launch_bounds__(256)
void ln_kernel(const float* __restrict__ x, const float* __restrict__ w, const float* __restrict__ b,
               bf16* __restrict__ out)
{
    const int D = 1024;
    const long row = blockIdx.x;
    const int t = threadIdx.x;
    f32x4 xv = *(const f32x4*)(x + row * D + t * 4);
    float s  = xv[0] + xv[1] + xv[2] + xv[3];
    float s2 = xv[0] * xv[0] + xv[1] * xv[1] + xv[2] * xv[2] + xv[3] * xv[3];
#pragma unroll
    for (int off = 32; off; off >>= 1) { s += __shfl_xor(s, off); s2 += __shfl_xor(s2, off); }
    __shared__ float ls[4], ls2[4];
    if ((t & 63) == 0) { ls[t >> 6] = s; ls2[t >> 6] = s2; }
    __syncthreads();
    s = ls[0] + ls[1] + ls[2] + ls[3];
    s2 = ls2[0] + ls2[1] + ls2[2] + ls2[3];
    float mu = s / D;
    float var = fmaxf(s2 / D - mu * mu, 0.f);
    float rstd = rsqrtf(var + 1e-5f);
#pragma unroll
    for (int i = 0; i < 4; i++) {
        int c = t * 4 + i;
        float v = (xv[i] - mu) * rstd * w[c] + b[c];
        out[row * D + c] = (bf16)CLAMP(v);
    }
}

// ---------------- GEMM 128x128 tile (Wo, FFN2), BK=64 (2x BK32 subtiles), dbuf ----------------
// r8 post-mortem: per-barrier-step fixed cost ~2200cy dominates (sync mechanics null'd
// twice). Fix: double work per step. Each 64-K step = two BK32 subtiles, each keeping the
// conflict-free [row][32] 64B-row layout (plain BK=64 rows would 16-way bank-conflict).
// MODE 0: out bf16 = clamp(acc)                               (qkv)
// MODE 1: out bf16 = clamp(relu(acc + bias_f32[n]))           (FFN inner)
// MODE 2: out f32  = clamp(acc + resid_f32[m,n])              (x1 = ctx@Wo + x)
// MODE 3: out f32  = clamp(acc + bias_f32[n] + resid_f32[m,n])(final out)
// MODE 4: out f32 += clamp(acc)                               (k-split accumulate)
template <int MODE>
__global__ __launch_bounds__(256)
void gemm_bt(const bf16* __restrict__ A, int lda, const bf16* __restrict__ Bt, int ldb,
             int M, int N, int K,
             const float* __restrict__ bias, const float* __restrict__ resid,
             void* __restrict__ outv, int ldo)
{
    __shared__ bf16 sA[2][2][128 * 32];   // [buf][khalf][row*32+col] — 32 KB
    __shared__ bf16 sB[2][2][128 * 32];   // 32 KB
    const int t = threadIdx.x;
    const int wave = t >> 6, lane = t & 63;
    const int wr = wave >> 1, wc = wave & 1;      // 2x2 wave grid, 64x64 per wave
    const int quad = lane >> 4, l16 = lane & 15;
    int bx = blockIdx.x, by = blockIdx.y;
    xcd_swizzle(bx, by);
    const int bm = by * 128, bn = bx * 128;

    f32x4 acc[4][4];
#pragma unroll
    for (int i = 0; i < 4; i++)
#pragma unroll
        for (int j = 0; j < 4; j++) acc[i][j] = f32x4{0.f, 0.f, 0.f, 0.f};

    const int srow = wave * 16 + (lane >> 2);     // global row within tile
    const int scol = (lane & 3) * 8;              // halfword col group (16B)
    const bf16* ga = A + (long)(bm + srow) * lda + scol;
    const bf16* gb = Bt + (long)(bn + srow) * ldb + scol;
    const int lbase = wave * 16 * 32;             // wave-uniform LDS base (halfwords)

#define STAGE128(buf, k0)                                                          \
    do {                                                                           \
        gload_lds16(ga + (k0), &sA[buf][0][lbase]);                                \
        gload_lds16(gb + (k0), &sB[buf][0][lbase]);                                \
        gload_lds16(ga + (long)64 * lda + (k0), &sA[buf][0][lbase + 64 * 32]);     \
        gload_lds16(gb + (long)64 * ldb + (k0), &sB[buf][0][lbase + 64 * 32]);     \
        gload_lds16(ga + (k0) + 32, &sA[buf][1][lbase]);                           \
        gload_lds16(gb + (k0) + 32, &sB[buf][1][lbase]);                           \
        gload_lds16(ga + (long)64 * lda + (k0) + 32, &sA[buf][1][lbase + 64 * 32]);\
        gload_lds16(gb + (long)64 * ldb + (k0) + 32, &sB[buf][1][lbase + 64 * 32]);\
    } while (0)

    STAGE128(0, 0);
    __syncthreads();
    int cur = 0;
    for (int k0 = 0; k0 < K; k0 += 64) {
        if (k0 + 64 < K) STAGE128(cur ^ 1, k0 + 64);   // prefetch next 64-K tile
#pragma unroll
        for (int kh = 0; kh < 2; kh++) {
            bf16x8 af[4], bfv[4];
#pragma unroll
            for (int i = 0; i < 4; i++)
                af[i] = *(const bf16x8*)(&sA[cur][kh][(wr * 64 + i * 16 + l16) * 32 + quad * 8]);
#pragma unroll
            for (int j = 0; j < 4; j++)
                bfv[j] = *(const bf16x8*)(&sB[cur][kh][(wc * 64 + j * 16 + l16) * 32 + quad * 8]);
#pragma unroll
            for (int i = 0; i < 4; i++)
#pragma unroll
                for (int j = 0; j < 4; j++)
                    acc[i][j] = __builtin_amdgcn_mfma_f32_16x16x32_bf16(af[i], bfv[j], acc[i][j], 0, 0, 0);
        }
        __syncthreads();                               // drains prefetch vmcnt + read sync
        cur ^= 1;
    }
#undef STAGE128

    float bv[4];
    if constexpr (MODE == 1 || MODE == 3) {
#pragma unroll
        for (int j = 0; j < 4; j++) bv[j] = bias[bn + wc * 64 + j * 16 + l16];
    }
#pragma unroll
    for (int i = 0; i < 4; i++) {
        int m = bm + wr * 64 + i * 16 + quad * 4;
#pragma unroll
        for (int j = 0; j < 4; j++) {
            int n = bn + wc * 64 + j * 16 + l16;
#pragma unroll
            for (int r = 0; r < 4; r++) {
                float v = acc[i][j][r];
                long idx = (long)(m + r) * ldo + n;
                if constexpr (MODE == 0) {
                    ((bf16*)outv)[idx] = (bf16)CLAMP(v);
                } else if constexpr (MODE == 1) {
                    v += bv[j]; v = v > 0.f ? v : 0.f;
                    ((bf16*)outv)[idx] = (bf16)CLAMP(v);
                } else if constexpr (MODE == 2) {
                    ((float*)outv)[idx] = CLAMP(v + resid[idx]);
                } else if constexpr (MODE == 3) {
                    ((float*)outv)[idx] = CLAMP(v + bv[j] + resid[idx]);
                } else {   // MODE 4
                    ((float*)outv)[idx] += CLAMP(v);
                }
            }
        }
    }
}

// ---------------- GEMM 256x256 tile (QKV, FFN1), BK=64 (2x BK32 subtiles), counted vmcnt ----------------
// 512 threads = 8 waves (2x4 grid, 128x64/wave). LDS 128 KB (precedent: m201 256^2 kernel).
// Schedule: stage 2 64-K tiles ahead; per step {2x(ds_read+32 MFMA); bar; STAGE(k+128);
// vmcnt(8) (keep newest 8 loads in flight); bar}. Per-step fixed cost amortized over
// 64 MFMA/wave instead of 32.
template <int MODE>
__global__ __launch_bounds__(512, 1)
void gemm256(const bf16* __restrict__ A, int lda, const bf16* __restrict__ Bt, int ldb,
             int M, int N, int K,
             const float* __restrict__ bias, const float* __restrict__ resid,
             void* __restrict__ outv, int ldo)
{
    __shared__ bf16 sA[2][2][256 * 32];   // [buf][khalf][...] — 64 KB
    __shared__ bf16 sB[2][2][256 * 32];   // 64 KB
    const int t = threadIdx.x;
    const int wave = t >> 6, lane = t & 63;
    const int wr = wave >> 2, wc = wave & 3;      // 2x4 wave grid, 128x64 per wave
    const int quad = lane >> 4, l16 = lane & 15;
    int bx = blockIdx.x, by = blockIdx.y;
    xcd_swizzle(bx, by);
    const int bm = by * 256, bn = bx * 256;

    f32x4 acc[8][4];
#pragma unroll
    for (int i = 0; i < 8; i++)
#pragma unroll
        for (int j = 0; j < 4; j++) acc[i][j] = f32x4{0.f, 0.f, 0.f, 0.f};

    // staging: 512 threads cover 128 rows per call (row = t>>2, colgroup = (t&3)*8)
    const int srow = t >> 2;
    const int scol = (t & 3) * 8;
    const bf16* ga = A + (long)(bm + srow) * lda + scol;
    const bf16* gb = Bt + (long)(bn + srow) * ldb + scol;
    const int lbase = wave * 16 * 32;             // wave-uniform LDS base (lane*16B contiguous)

#define STAGE256(buf, k0)                                                            \
    do {                                                                             \
        gload_lds16(ga + (k0), &sA[buf][0][lbase]);                                  \
        gload_lds16(gb + (k0), &sB[buf][0][lbase]);                                  \
        gload_lds16(ga + (long)128 * lda + (k0), &sA[buf][0][lbase + 128 * 32]);     \
        gload_lds16(gb + (long)128 * ldb + (k0), &sB[buf][0][lbase + 128 * 32]);     \
        gload_lds16(ga + (k0) + 32, &sA[buf][1][lbase]);                             \
        gload_lds16(gb + (k0) + 32, &sB[buf][1][lbase]);                             \
        gload_lds16(ga + (long)128 * lda + (k0) + 32, &sA[buf][1][lbase + 128 * 32]);\
        gload_lds16(gb + (long)128 * ldb + (k0) + 32, &sB[buf][1][lbase + 128 * 32]);\
    } while (0)

    STAGE256(0, 0);                                    // 8 loads in flight
    if (K > 64) STAGE256(1, 64);                       // 16 in flight
    asm volatile("s_waitcnt vmcnt(8)" ::: "memory");   // buf0 landed (oldest 8)
    __builtin_amdgcn_s_barrier();                      // all waves: buf0 ready
    int cur = 0;
    for (int k0 = 0; k0 < K; k0 += 64) {
#pragma unroll
        for (int kh = 0; kh < 2; kh++) {
            bf16x8 af[8], bfv[4];
#pragma unroll
            for (int i = 0; i < 8; i++)
                af[i] = *(const bf16x8*)(&sA[cur][kh][(wr * 128 + i * 16 + l16) * 32 + quad * 8]);
#pragma unroll
            for (int j = 0; j < 4; j++)
                bfv[j] = *(const bf16x8*)(&sB[cur][kh][(wc * 64 + j * 16 + l16) * 32 + quad * 8]);
#pragma unroll
            for (int i = 0; i < 8; i++)
#pragma unroll
                for (int j = 0; j < 4; j++)
                    acc[i][j] = __builtin_amdgcn_mfma_f32_16x16x32_bf16(af[i], bfv[j], acc[i][j], 0, 0, 0);
        }
        __builtin_amdgcn_s_barrier();                  // all waves done READING buf[cur]
        if (k0 + 128 < K) {
            STAGE256(cur, k0 + 128);                   // overwrite cur with tile k+2
            asm volatile("s_waitcnt vmcnt(8)" ::: "memory");  // older tile (next read) landed
        } else {
            asm volatile("s_waitcnt vmcnt(0)" ::: "memory");  // tail drain
        }
        __builtin_amdgcn_s_barrier();                  // all waves: next buf ready
        cur ^= 1;
    }
#undef STAGE256

    float bv[4];
    if constexpr (MODE == 1 || MODE == 3) {
#pragma unroll
        for (int j = 0; j < 4; j++) bv[j] = bias[bn + wc * 64 + j * 16 + l16];
    }
#pragma unroll
    for (int i = 0; i < 8; i++) {
        int m = bm + wr * 128 + i * 16 + quad * 4;
#pragma unroll
        for (int j = 0; j < 4; j++) {
            int n = bn + wc * 64 + j * 16 + l16;
#pragma unroll
            for (int r = 0; r < 4; r++) {
                float v = acc[i][j][r];
                long idx = (long)(m + r) * ldo + n;
                if constexpr (MODE == 0) {
                    ((bf16*)outv)[idx] = (bf16)CLAMP(v);
                } else if constexpr (MODE == 1) {
                    v += bv[j]; v = v > 0.f ? v : 0.f;
                    ((bf16*)outv)[idx] = (bf16)CLAMP(v);
                } else if constexpr (MODE == 2) {
                    ((float*)outv)[idx] = CLAMP(v + resid[idx]);
                } else if constexpr (MODE == 3) {
                    ((float*)outv)[idx] = CLAMP(v + bv[j] + resid[idx]);
                } else {   // MODE 4
                    ((float*)outv)[idx] += CLAMP(v);
                }
            }
        }
    }
}

// ---------------- MFMA causal flash attention, S^T formulation, DIAGONAL-PAIRED ----------------
#define SM_C 0.1803368801111f   // 0.125 * log2(e)

static __device__ __forceinline__ void attn_tile(
    const bf16x8 kf[4][2], const bf16* sVt, int t0, int qpb,
    int quad, int l16,
    const bf16x8 qf[2][2], f32x4 o[2][4], float* m_i, float* l_i)
{
    if (t0 > qpb + 31) return;    // whole wave-tile causally masked
    bf16x4 pb[2][4];
#pragma unroll
    for (int rf = 0; rf < 2; rf++) {
        f32x4 sc[4];
#pragma unroll
        for (int tt = 0; tt < 4; tt++) {
            f32x4 s4 = f32x4{0.f, 0.f, 0.f, 0.f};
            s4 = __builtin_amdgcn_mfma_f32_16x16x32_bf16(kf[tt][0], qf[rf][0], s4, 0, 0, 0);
            s4 = __builtin_amdgcn_mfma_f32_16x16x32_bf16(kf[tt][1], qf[rf][1], s4, 0, 0, 0);
            sc[tt] = s4;
        }
        const int qpos = qpb + rf * 16 + l16;
        if (t0 + 63 > qpb + rf * 16) {            // boundary tile: mask (wave-uniform branch)
#pragma unroll
            for (int tt = 0; tt < 4; tt++)
#pragma unroll
                for (int r = 0; r < 4; r++) {
                    int tcol = t0 + tt * 16 + quad * 4 + r;
                    float v = sc[tt][r] * SM_C;
                    sc[tt][r] = (tcol > qpos) ? NEGINF : v;
                }
        } else {                                   // interior tile: no mask VALU
#pragma unroll
            for (int tt = 0; tt < 4; tt++)
#pragma unroll
                for (int r = 0; r < 4; r++) sc[tt][r] = sc[tt][r] * SM_C;
        }
        float t4[4];
#pragma unroll
        for (int tt = 0; tt < 4; tt++)
            t4[tt] = fmaxf(fmaxf(sc[tt][0], sc[tt][1]), fmaxf(sc[tt][2], sc[tt][3]));
        float mt = fmaxf(fmaxf(t4[0], t4[1]), fmaxf(t4[2], t4[3]));
        mt = fmaxf(mt, __shfl_xor(mt, 16));
        mt = fmaxf(mt, __shfl_xor(mt, 32));
        float mn = fmaxf(m_i[rf], mt);
        float alpha = exp2fast(m_i[rf] - mn);
        m_i[rf] = mn;
        float lt4[4];
#pragma unroll
        for (int tt = 0; tt < 4; tt++) {
            float e0 = exp2fast(sc[tt][0] - mn);
            float e1 = exp2fast(sc[tt][1] - mn);
            float e2 = exp2fast(sc[tt][2] - mn);
            float e3 = exp2fast(sc[tt][3] - mn);
            sc[tt][0] = e0; sc[tt][1] = e1; sc[tt][2] = e2; sc[tt][3] = e3;
            lt4[tt] = (e0 + e1) + (e2 + e3);
        }
        float lt = (lt4[0] + lt4[1]) + (lt4[2] + lt4[3]);
        lt += __shfl_xor(lt, 16);
        lt += __shfl_xor(lt, 32);
        l_i[rf] = l_i[rf] * alpha + lt;
#pragma unroll
        for (int jb = 0; jb < 4; jb++)
#pragma unroll
            for (int r = 0; r < 4; r++) o[rf][jb][r] *= alpha;
#pragma unroll
        for (int tt = 0; tt < 4; tt++)
            pb[rf][tt] = bf16x4{(bf16)sc[tt][0], (bf16)sc[tt][1], (bf16)sc[tt][2], (bf16)sc[tt][3]};
    }
    // PV: O^T += V^T . P^T  (16x16x16, K-accumulate over tt)
#pragma unroll
    for (int jb = 0; jb < 4; jb++) {
#pragma unroll
        for (int tt = 0; tt < 4; tt++) {
            bf16x4 va = *(const bf16x4*)(&sVt[(jb * 16 + l16) * 72 + tt * 16 + quad * 4]);
            o[0][jb] = mfma16(va, pb[0][tt], o[0][jb]);
            o[1][jb] = mfma16(va, pb[1][tt], o[1][jb]);
        }
    }
}

__global__ __launch_bounds__(256, 2)
void attn_kernel(const bf16* __restrict__ qkv, const bf16* __restrict__ Vt, bf16* __restrict__ ctx)
{
    const int bh = blockIdx.x;
    const int p  = blockIdx.y;            // diagonal pair 0..7
    const int b = bh >> 4, h = bh & 15;
    const int t = threadIdx.x;
    const int wave = t >> 6, lane = t & 63;
    const int quad = lane >> 4, l16 = lane & 15;
    const long RS = 3072;
    const int qb0 = p, qb1 = 15 - p;
    const int nt0 = 2 * p + 2, nt1 = 32 - 2 * p;

    __shared__ bf16 sK[64 * 72];      // [t][d]
    __shared__ bf16 sVt[64 * 72];     // [d][t]

    bf16x8 qf[2][2][2];
#pragma unroll
    for (int s = 0; s < 2; s++) {
        const int qb = s ? qb1 : qb0;
#pragma unroll
        for (int rf = 0; rf < 2; rf++) {
            const bf16* qp = qkv + (long)(b * 2048 + qb * 128 + wave * 32 + rf * 16 + l16) * RS + h * 64 + quad * 8;
            qf[s][rf][0] = *(const bf16x8*)(qp);
            qf[s][rf][1] = *(const bf16x8*)(qp + 32);
        }
    }
    f32x4 o[2][2][4];                  // [s][rf][jb]
#pragma unroll
    for (int s = 0; s < 2; s++)
#pragma unroll
        for (int rf = 0; rf < 2; rf++)
#pragma unroll
            for (int jb = 0; jb < 4; jb++) o[s][rf][jb] = f32x4{0.f, 0.f, 0.f, 0.f};
    float m_i[2][2] = {{NEGINF, NEGINF}, {NEGINF, NEGINF}};
    float l_i[2][2] = {{0.f, 0.f}, {0.f, 0.f}};
    const int qpb0 = qb0 * 128 + wave * 32;
    const int qpb1 = qb1 * 128 + wave * 32;

    const int cg = (t & 7) * 8, rr = t >> 3;
    const bf16* Kbase  = qkv + (long)(b * 2048) * RS + 1024 + h * 64;
    const bf16* Vtbase = Vt + ((long)bh * 64) * 2048;

    bf16x8 kreg[2], vreg[2];
#pragma unroll
    for (int pp = 0; pp < 2; pp++) {   // prefetch tile 0
        kreg[pp] = *(const bf16x8*)(Kbase + (long)(pp * 32 + rr) * RS + cg);
        vreg[pp] = *(const bf16x8*)(Vtbase + (long)(pp * 32 + rr) * 2048 + cg);
    }

    for (int ti = 0; ti < nt1; ti++) {
        __syncthreads();
#pragma unroll
        for (int pp = 0; pp < 2; pp++) {
            *(bf16x8*)(&sK[(pp * 32 + rr) * 72 + cg]) = kreg[pp];
            *(bf16x8*)(&sVt[(pp * 32 + rr) * 72 + cg]) = vreg[pp];
        }
        __syncthreads();
        if (ti + 1 < nt1) {
            int t0n = (ti + 1) * 64;
#pragma unroll
            for (int pp = 0; pp < 2; pp++) {
                kreg[pp] = *(const bf16x8*)(Kbase + (long)(t0n + pp * 32 + rr) * RS + cg);
                vreg[pp] = *(const bf16x8*)(Vtbase + (long)(pp * 32 + rr) * 2048 + t0n + cg);
            }
        }
        const int t0 = ti * 64;

        bf16x8 kf[4][2];
#pragma unroll
        for (int tt = 0; tt < 4; tt++) {
            kf[tt][0] = *(const bf16x8*)(&sK[(tt * 16 + l16) * 72 + quad * 8]);
            kf[tt][1] = *(const bf16x8*)(&sK[(tt * 16 + l16) * 72 + 32 + quad * 8]);
        }
        if (ti < nt0)
            attn_tile(kf, sVt, t0, qpb0, quad, l16, qf[0], o[0], m_i[0], l_i[0]);
        attn_tile(kf, sVt, t0, qpb1, quad, l16, qf[1], o[1], m_i[1], l_i[1]);
    }
#pragma unroll
    for (int s = 0; s < 2; s++) {
        const int qpb = s ? qpb1 : qpb0;
#pragma unroll
        for (int rf = 0; rf < 2; rf++) {
            float rl = 1.0f / l_i[s][rf];
            const long row = (long)(b * 2048 + qpb + rf * 16 + l16) * 1024 + h * 64;
#pragma unroll
            for (int jb = 0; jb < 4; jb++) {
                bf16x4 ov;
#pragma unroll
                for (int r = 0; r < 4; r++) ov[r] = (bf16)CLAMP(o[s][rf][jb][r] * rl);
                *(bf16x4*)(&ctx[row + jb * 16 + quad * 4]) = ov;
            }
        }
    }
}

// ---------------- confidence head (f32) ----------------
__global__ __launch_bounds__(256)
void conf_partial(const float* __restrict__ xout, const float* __restrict__ cw, float* __restrict__ part)
{
    int blk = blockIdx.x;
    int b = blk >> 6, chunk = blk & 63;
    int t = threadIdx.x;
    int d0 = t * 4;
    f32x4 w = *(const f32x4*)(cw + d0);
    float acc = 0.f;
    for (int s = chunk * 32; s < chunk * 32 + 32; s++) {
        f32x4 v = *(const f32x4*)(xout + (long)(b * 2048 + s) * 1024 + d0);
        acc += v[0] * w[0] + v[1] * w[1] + v[2] * w[2] + v[3] * w[3];
    }
#pragma unroll
    for (int off = 32; off; off >>= 1) acc += __shfl_xor(acc, off);
    __shared__ float ls[4];
    if ((t & 63) == 0) ls[t >> 6] = acc;
    __syncthreads();
    if (t == 0) part[blk] = ls[0] + ls[1] + ls[2] + ls[3];
}

__global__ void conf_final(const float* __restrict__ part, const float* __restrict__ cb, float* __restrict__ outp)
{
    if (threadIdx.x == 0) {
        float accb = 0.f;
        for (int b = 0; b < 4; b++) {
            float s = 0.f;
            for (int i = 0; i < 64; i++) s += part[b * 64 + i];
            float z = s / 2048.0f + cb[0];
            accb += 1.0f / (1.0f + expf(-z));
        }
        outp[0] = accb * 0.25f;
    }
}

// ---------------- launch ----------------
// Workspace (1 MB = 1<<20), peak 96 MB + 1 KB, phase-disjoint aliasing:
//  [ 0, 8): WqkvT (ph1-3) -> W1T (ph6+)
//  [ 8,16): WoT (ph1-5)   -> W2T (ph6+)
//  [16,32): h (ph2-3) -> ctx (ph4-5) -> h2 (ph7-9)
//  [32,80): qkv (ph3-4); x1 f32 [32,64) ph5+ (qkv dead)
//  [80,96): Vt (ph3.5-4); a1h [64,96) ph8-9 (qkv tail + Vt dead)
//  [96MB):  part f32[256]
extern "C" void kernel_launch(void* const* d_in, const int* in_sizes, int n_in,
                              void* d_out, int out_size, void* d_ws, size_t ws_size,
                              hipStream_t stream)
{
    const int D = 1024, F = 4096, M = 8192;
    const size_t MB = 1u << 20;
    const float* x     = (const float*)d_in[0];
    const float* Wq    = (const float*)d_in[1];
    const float* Wk    = (const float*)d_in[2];
    const float* Wv    = (const float*)d_in[3];
    const float* Wo    = (const float*)d_in[4];
    const float* ln1w  = (const float*)d_in[5];
    const float* ln1b  = (const float*)d_in[6];
    const float* W1    = (const float*)d_in[7];
    const float* b1    = (const float*)d_in[8];
    const float* W2    = (const float*)d_in[9];
    const float* b2    = (const float*)d_in[10];
    const float* ln2w  = (const float*)d_in[11];
    const float* ln2b  = (const float*)d_in[12];
    const float* confw = (const float*)d_in[13];
    const float* confb = (const float*)d_in[14];
    float* out = (float*)d_out;

    char* ws = (char*)d_ws;
    bf16*  WqkvT = (bf16*)(ws);
    bf16*  WoT   = (bf16*)(ws + 8 * MB);
    bf16*  h     = (bf16*)(ws + 16 * MB);
    bf16*  qkv   = (bf16*)(ws + 32 * MB);
    bf16*  Vt    = (bf16*)(ws + 80 * MB);
    bf16*  ctx   = (bf16*)(ws + 16 * MB);
    float* x1    = (float*)(ws + 32 * MB);
    bf16*  h2    = (bf16*)(ws + 16 * MB);
    bf16*  W1T   = (bf16*)(ws);
    bf16*  W2T   = (bf16*)(ws + 8 * MB);
    bf16*  a1h   = (bf16*)(ws + 64 * MB);
    float* part  = (float*)(ws + 96 * MB);

    dim3 tb(32, 8);
    // ph1: QKV/Wo weight transposes in one launch
    transpose4_kernel<<<dim3(32, 32, 4), tb, 0, stream>>>(Wq, Wk, Wv, Wo, WqkvT, WoT);
    // ph2: LN1
    ln_kernel<<<M, 256, 0, stream>>>(x, ln1w, ln1b, h);
    // ph3: QKV projection (256^2 tile: 384 blocks)
    gemm256<0><<<dim3(12, 32), 512, 0, stream>>>(h, D, WqkvT, D, M, 3 * D, D, nullptr, nullptr, qkv, 3 * D);
    // ph3.5: V transpose
    v_transpose<<<dim3(64, 2, 64), tb, 0, stream>>>(qkv, Vt);
    // ph4: attention (diagonal-paired: 512 uniform blocks, fully co-resident)
    attn_kernel<<<dim3(64, 8), 256, 0, stream>>>(qkv, Vt, ctx);
    // ph5: Wo projection + residual -> x1 f32 (128^2: 512 blocks)
    gemm_bt<2><<<dim3(8, 64), 256, 0, stream>>>(ctx, D, WoT, D, M, D, D, nullptr, x, x1, D);
    // ph6: FFN weight transposes
    transpose_kernel<<<dim3(F / 32, D / 32), tb, 0, stream>>>(W1, W1T, D, F);
    transpose_kernel<<<dim3(D / 32, F / 32), tb, 0, stream>>>(W2, W2T, F, D);
    // ph7: LN2
    ln_kernel<<<M, 256, 0, stream>>>(x1, ln2w, ln2b, h2);
    // ph8: FFN half 1 (inner 256^2: 256 blocks; outer 128^2 k-split accumulate)
    gemm256<1><<<dim3(8, 32), 512, 0, stream>>>(h2, D, W1T, D, M, 2048, D, b1, nullptr, a1h, 2048);
    gemm_bt<4><<<dim3(8, 64), 256, 0, stream>>>(a1h, 2048, W2T, F, M, D, 2048, nullptr, nullptr, x1, D);
    // ph9: FFN half 2 -> out f32
    gemm256<1><<<dim3(8, 32), 512, 0, stream>>>(h2, D, W1T + (size_t)2048 * D, D, M, 2048, D, b1 + 2048, nullptr, a1h, 2048);
    gemm_bt<3><<<dim3(8, 64), 256, 0, stream>>>(a1h, 2048, W2T + 2048, F, M, D, 2048, b2, x1, out, D);
    // ph10: confidence head
    conf_partial<<<256, 256, 0, stream>>>(out, confw, part);
    conf_final<<<1, 64, 0, stream>>>(part, confb, out + (size_t)M * D);
}

// Round 10
// 539.286 us; speedup vs baseline: 1.0905x; 1.0283x over previous
//
#include <hip/hip_runtime.h>
#include <hip/hip_bf16.h>
#include <math.h>

typedef __bf16 bf16;
typedef __bf16 bf16x8 __attribute__((ext_vector_type(8)));
typedef __bf16 bf16x4 __attribute__((ext_vector_type(4)));
typedef float  f32x4  __attribute__((ext_vector_type(4)));
typedef short  s16x4  __attribute__((ext_vector_type(4)));

#define CLAMP(v) fminf(fmaxf((v), -100.f), 100.f)   // NaN tripwire; legit |v| <= ~40
#define NEGINF (-1e30f)

// native 2^x (v_exp_f32). __exp2f collides with glibc macros; use the amdgcn builtin.
static __device__ __forceinline__ float exp2fast(float x)
{
#if __has_builtin(__builtin_amdgcn_exp2f)
    return __builtin_amdgcn_exp2f(x);
#else
    return exp2f(x);
#endif
}

// K=16 bf16 MFMA (PV stage): builtin name differs across ROCm versions
static __device__ __forceinline__ f32x4 mfma16(bf16x4 a, bf16x4 b, f32x4 c)
{
#if __has_builtin(__builtin_amdgcn_mfma_f32_16x16x16_bf16)
    return __builtin_amdgcn_mfma_f32_16x16x16_bf16(a, b, c, 0, 0, 0);
#else
    s16x4 as, bs;
    __builtin_memcpy(&as, &a, 8);
    __builtin_memcpy(&bs, &b, 8);
    return __builtin_amdgcn_mfma_f32_16x16x16bf16_1k(as, bs, c, 0, 0, 0);
#endif
}

// async global -> LDS, 16B per lane. LDS dest is wave-uniform base + lane*16;
// global src is per-lane. (learn_hip m97 pattern)
static __device__ __forceinline__ void gload_lds16(const bf16* g, bf16* l)
{
    __builtin_amdgcn_global_load_lds(
        (const __attribute__((address_space(1))) void*)g,
        (__attribute__((address_space(3))) void*)l, 16, 0, 0);
}

// XCD-aware bijective block swizzle (T1, m157/m204): requires nwg % 8 == 0.
static __device__ __forceinline__ void xcd_swizzle(int& bx, int& by)
{
    int gx = gridDim.x, nwg = gx * gridDim.y;
    int lin = by * gx + bx;
    int cpx = nwg >> 3;
    int swz = (lin & 7) * cpx + (lin >> 3);
    bx = swz % gx;
    by = swz / gx;
}

// ---------------- 4x weight transpose + cast: dst_bf16[C][R] = src_f32[R][C], D x D ----------------
__global__ __launch_bounds__(256)
void transpose4_kernel(const float* __restrict__ Wq, const float* __restrict__ Wk,
                       const float* __restrict__ Wv, const float* __restrict__ Wo,
                       bf16* __restrict__ dstQKV, bf16* __restrict__ dstO)
{
    const int D = 1024;
    const float* src = (blockIdx.z == 0) ? Wq : (blockIdx.z == 1) ? Wk : (blockIdx.z == 2) ? Wv : Wo;
    bf16* dst = (blockIdx.z < 3) ? dstQKV + (size_t)blockIdx.z * D * D : dstO;
    __shared__ float tile[32][33];
    int c0 = blockIdx.x * 32, r0 = blockIdx.y * 32;
    int tx = threadIdx.x, ty = threadIdx.y;   // block (32,8)
#pragma unroll
    for (int i = 0; i < 4; i++)
        tile[ty + i * 8][tx] = src[(long)(r0 + ty + i * 8) * D + c0 + tx];
    __syncthreads();
#pragma unroll
    for (int i = 0; i < 4; i++)
        dst[(long)(c0 + ty + i * 8) * D + r0 + tx] = (bf16)tile[tx][ty + i * 8];
}

// ---------------- generic weight transpose + cast (W1/W2) ----------------
__global__ __launch_bounds__(256)
void transpose_kernel(const float* __restrict__ src, bf16* __restrict__ dst, int R, int C)
{
    __shared__ float tile[32][33];
    int c0 = blockIdx.x * 32, r0 = blockIdx.y * 32;
    int tx = threadIdx.x, ty = threadIdx.y;
#pragma unroll
    for (int i = 0; i < 4; i++)
        tile[ty + i * 8][tx] = src[(long)(r0 + ty + i * 8) * C + c0 + tx];
    __syncthreads();
#pragma unroll
    for (int i = 0; i < 4; i++)
        dst[(long)(c0 + ty + i * 8) * R + r0 + tx] = (bf16)tile[tx][ty + i * 8];
}

// ---------------- V transpose: Vt[bh][d][t] = qkv[(b*2048+t)*3072 + 2048 + h*64 + d] ----------------
__global__ __launch_bounds__(256)
void v_transpose(const bf16* __restrict__ qkv, bf16* __restrict__ Vt)
{
    __shared__ bf16 tile[32][33];
    int bh = blockIdx.z, b = bh >> 4, h = bh & 15;
    int t0 = blockIdx.x * 32, d0 = blockIdx.y * 32;
    int tx = threadIdx.x, ty = threadIdx.y;
#pragma unroll
    for (int i = 0; i < 4; i++)
        tile[ty + i * 8][tx] = qkv[(long)(b * 2048 + t0 + ty + i * 8) * 3072 + 2048 + h * 64 + d0 + tx];
    __syncthreads();
#pragma unroll
    for (int i = 0; i < 4; i++)
        Vt[((long)bh * 64 + d0 + ty + i * 8) * 2048 + t0 + tx] = tile[tx][ty + i * 8];
}

// ---------------- layernorm (row per block, D=1024, 256 thr), f32 in -> bf16 out ----------------
__global__ __launch_bounds__(256)
void ln_kernel(const float* __restrict__ x, const float* __restrict__ w, const float* __restrict__ b,
               bf16* __restrict__ out)
{
    const int D = 1024;
    const long row = blockIdx.x;
    const int t = threadIdx.x;
    f32x4 xv = *(const f32x4*)(x + row * D + t * 4);
    float s  = xv[0] + xv[1] + xv[2] + xv[3];
    float s2 = xv[0] * xv[0] + xv[1] * xv[1] + xv[2] * xv[2] + xv[3] * xv[3];
#pragma unroll
    for (int off = 32; off; off >>= 1) { s += __shfl_xor(s, off); s2 += __shfl_xor(s2, off); }
    __shared__ float ls[4], ls2[4];
    if ((t & 63) == 0) { ls[t >> 6] = s; ls2[t >> 6] = s2; }
    __syncthreads();
    s = ls[0] + ls[1] + ls[2] + ls[3];
    s2 = ls2[0] + ls2[1] + ls2[2] + ls2[3];
    float mu = s / D;
    float var = fmaxf(s2 / D - mu * mu, 0.f);
    float rstd = rsqrtf(var + 1e-5f);
#pragma unroll
    for (int i = 0; i < 4; i++) {
        int c = t * 4 + i;
        float v = (xv[i] - mu) * rstd * w[c] + b[c];
        out[row * D + c] = (bf16)CLAMP(v);
    }
}

// ---------------- GEMM 128x128 tile (Wo, FFN2), BK=64 (2x BK32 subtiles), dbuf ----------------
// (r9 structure, unchanged — control for the gemm256 phase-split experiment)
// MODE 0: out bf16 = clamp(acc)                               (qkv)
// MODE 1: out bf16 = clamp(relu(acc + bias_f32[n]))           (FFN inner)
// MODE 2: out f32  = clamp(acc + resid_f32[m,n])              (x1 = ctx@Wo + x)
// MODE 3: out f32  = clamp(acc + bias_f32[n] + resid_f32[m,n])(final out)
// MODE 4: out f32 += clamp(acc)                               (k-split accumulate)
template <int MODE>
__global__ __launch_bounds__(256)
void gemm_bt(const bf16* __restrict__ A, int lda, const bf16* __restrict__ Bt, int ldb,
             int M, int N, int K,
             const float* __restrict__ bias, const float* __restrict__ resid,
             void* __restrict__ outv, int ldo)
{
    __shared__ bf16 sA[2][2][128 * 32];   // [buf][khalf][row*32+col] — 32 KB
    __shared__ bf16 sB[2][2][128 * 32];   // 32 KB
    const int t = threadIdx.x;
    const int wave = t >> 6, lane = t & 63;
    const int wr = wave >> 1, wc = wave & 1;      // 2x2 wave grid, 64x64 per wave
    const int quad = lane >> 4, l16 = lane & 15;
    int bx = blockIdx.x, by = blockIdx.y;
    xcd_swizzle(bx, by);
    const int bm = by * 128, bn = bx * 128;

    f32x4 acc[4][4];
#pragma unroll
    for (int i = 0; i < 4; i++)
#pragma unroll
        for (int j = 0; j < 4; j++) acc[i][j] = f32x4{0.f, 0.f, 0.f, 0.f};

    const int srow = wave * 16 + (lane >> 2);     // global row within tile
    const int scol = (lane & 3) * 8;              // halfword col group (16B)
    const bf16* ga = A + (long)(bm + srow) * lda + scol;
    const bf16* gb = Bt + (long)(bn + srow) * ldb + scol;
    const int lbase = wave * 16 * 32;             // wave-uniform LDS base (halfwords)

#define STAGE128(buf, k0)                                                          \
    do {                                                                           \
        gload_lds16(ga + (k0), &sA[buf][0][lbase]);                                \
        gload_lds16(gb + (k0), &sB[buf][0][lbase]);                                \
        gload_lds16(ga + (long)64 * lda + (k0), &sA[buf][0][lbase + 64 * 32]);     \
        gload_lds16(gb + (long)64 * ldb + (k0), &sB[buf][0][lbase + 64 * 32]);     \
        gload_lds16(ga + (k0) + 32, &sA[buf][1][lbase]);                           \
        gload_lds16(gb + (k0) + 32, &sB[buf][1][lbase]);                           \
        gload_lds16(ga + (long)64 * lda + (k0) + 32, &sA[buf][1][lbase + 64 * 32]);\
        gload_lds16(gb + (long)64 * ldb + (k0) + 32, &sB[buf][1][lbase + 64 * 32]);\
    } while (0)

    STAGE128(0, 0);
    __syncthreads();
    int cur = 0;
    for (int k0 = 0; k0 < K; k0 += 64) {
        if (k0 + 64 < K) STAGE128(cur ^ 1, k0 + 64);   // prefetch next 64-K tile
#pragma unroll
        for (int kh = 0; kh < 2; kh++) {
            bf16x8 af[4], bfv[4];
#pragma unroll
            for (int i = 0; i < 4; i++)
                af[i] = *(const bf16x8*)(&sA[cur][kh][(wr * 64 + i * 16 + l16) * 32 + quad * 8]);
#pragma unroll
            for (int j = 0; j < 4; j++)
                bfv[j] = *(const bf16x8*)(&sB[cur][kh][(wc * 64 + j * 16 + l16) * 32 + quad * 8]);
#pragma unroll
            for (int i = 0; i < 4; i++)
#pragma unroll
                for (int j = 0; j < 4; j++)
                    acc[i][j] = __builtin_amdgcn_mfma_f32_16x16x32_bf16(af[i], bfv[j], acc[i][j], 0, 0, 0);
        }
        __syncthreads();                               // drains prefetch vmcnt + read sync
        cur ^= 1;
    }
#undef STAGE128

    float bv[4];
    if constexpr (MODE == 1 || MODE == 3) {
#pragma unroll
        for (int j = 0; j < 4; j++) bv[j] = bias[bn + wc * 64 + j * 16 + l16];
    }
#pragma unroll
    for (int i = 0; i < 4; i++) {
        int m = bm + wr * 64 + i * 16 + quad * 4;
#pragma unroll
        for (int j = 0; j < 4; j++) {
            int n = bn + wc * 64 + j * 16 + l16;
#pragma unroll
            for (int r = 0; r < 4; r++) {
                float v = acc[i][j][r];
                long idx = (long)(m + r) * ldo + n;
                if constexpr (MODE == 0) {
                    ((bf16*)outv)[idx] = (bf16)CLAMP(v);
                } else if constexpr (MODE == 1) {
                    v += bv[j]; v = v > 0.f ? v : 0.f;
                    ((bf16*)outv)[idx] = (bf16)CLAMP(v);
                } else if constexpr (MODE == 2) {
                    ((float*)outv)[idx] = CLAMP(v + resid[idx]);
                } else if constexpr (MODE == 3) {
                    ((float*)outv)[idx] = CLAMP(v + bv[j] + resid[idx]);
                } else {   // MODE 4
                    ((float*)outv)[idx] += CLAMP(v);
                }
            }
        }
    }
}

// ---------------- GEMM 256x256 tile (QKV, FFN1), BK=64, 4-PHASE interleave ----------------
// r9 analysis: barrier-locked bulk schedule serializes the CU's LDS burst (24 b128/wave,
// ~1536cy CU-wide) against the MFMA burst (~2480cy) -> ~4000cy/step. Phase-split (m196/
// m201 lever, +28-41% measured at this geometry): 4 phases per K-tile, clustered by
// (khalf, j-pair); each phase reads only its fragments then runs 16 MFMA under setprio.
// LDS traffic per phase ~640/128/640/128cy vs 620cy MFMA -> phases MFMA-bound.
// Safety: stages ALWAYS target the other buffer (nxt) -> no intra-tile LDS hazard ->
// intra-tile barriers are raw s_barrier (no vmcnt drain); tile boundary = __syncthreads
// (vmcnt+lgkm drain; stages issued ~3 phases earlier -> drain free).
template <int MODE>
__global__ __launch_bounds__(512, 1)
void gemm256(const bf16* __restrict__ A, int lda, const bf16* __restrict__ Bt, int ldb,
             int M, int N, int K,
             const float* __restrict__ bias, const float* __restrict__ resid,
             void* __restrict__ outv, int ldo)
{
    __shared__ bf16 sA[2][2][256 * 32];   // [buf][khalf][...] — 64 KB
    __shared__ bf16 sB[2][2][256 * 32];   // 64 KB
    const int t = threadIdx.x;
    const int wave = t >> 6, lane = t & 63;
    const int wr = wave >> 2, wc = wave & 3;      // 2x4 wave grid, 128x64 per wave
    const int quad = lane >> 4, l16 = lane & 15;
    int bx = blockIdx.x, by = blockIdx.y;
    xcd_swizzle(bx, by);
    const int bm = by * 256, bn = bx * 256;

    f32x4 acc[8][4];
#pragma unroll
    for (int i = 0; i < 8; i++)
#pragma unroll
        for (int j = 0; j < 4; j++) acc[i][j] = f32x4{0.f, 0.f, 0.f, 0.f};

    // staging: 512 threads cover 128 rows per call (row = t>>2, colgroup = (t&3)*8)
    const int srow = t >> 2;
    const int scol = (t & 3) * 8;
    const bf16* ga = A + (long)(bm + srow) * lda + scol;
    const bf16* gb = Bt + (long)(bn + srow) * ldb + scol;
    const int lbase = wave * 16 * 32;             // wave-uniform LDS base (lane*16B contiguous)

#define STAGE256(buf, k0)                                                            \
    do {                                                                             \
        gload_lds16(ga + (k0), &sA[buf][0][lbase]);                                  \
        gload_lds16(gb + (k0), &sB[buf][0][lbase]);                                  \
        gload_lds16(ga + (long)128 * lda + (k0), &sA[buf][0][lbase + 128 * 32]);     \
        gload_lds16(gb + (long)128 * ldb + (k0), &sB[buf][0][lbase + 128 * 32]);     \
        gload_lds16(ga + (k0) + 32, &sA[buf][1][lbase]);                             \
        gload_lds16(gb + (k0) + 32, &sB[buf][1][lbase]);                             \
        gload_lds16(ga + (long)128 * lda + (k0) + 32, &sA[buf][1][lbase + 128 * 32]);\
        gload_lds16(gb + (long)128 * ldb + (k0) + 32, &sB[buf][1][lbase + 128 * 32]);\
    } while (0)

    // fragment read helpers (conflict-floor [row][32] layout)
#define AFRD(kh, i) (*(const bf16x8*)(&sA[cur][kh][(wr * 128 + (i) * 16 + l16) * 32 + quad * 8]))
#define BFRD(kh, j) (*(const bf16x8*)(&sB[cur][kh][(wc * 64 + (j) * 16 + l16) * 32 + quad * 8]))

    STAGE256(0, 0);
    __syncthreads();                                   // prologue: tile 0 landed
    int cur = 0;
    for (int k0 = 0; k0 < K; k0 += 64) {
        const int nxt = cur ^ 1;
        bf16x8 af[8], b0, b1;
        // ---- phase 0: khalf 0, j={0,1}; issue all stages for tile t+1 -> nxt ----
#pragma unroll
        for (int i = 0; i < 8; i++) af[i] = AFRD(0, i);
        b0 = BFRD(0, 0); b1 = BFRD(0, 1);
        if (k0 + 64 < K) STAGE256(nxt, k0 + 64);
        __builtin_amdgcn_s_setprio(1);
#pragma unroll
        for (int i = 0; i < 8; i++) {
            acc[i][0] = __builtin_amdgcn_mfma_f32_16x16x32_bf16(af[i], b0, acc[i][0], 0, 0, 0);
            acc[i][1] = __builtin_amdgcn_mfma_f32_16x16x32_bf16(af[i], b1, acc[i][1], 0, 0, 0);
        }
        __builtin_amdgcn_s_setprio(0);
        __builtin_amdgcn_s_barrier();
        // ---- phase 1: khalf 0, j={2,3} ----
        b0 = BFRD(0, 2); b1 = BFRD(0, 3);
        __builtin_amdgcn_s_setprio(1);
#pragma unroll
        for (int i = 0; i < 8; i++) {
            acc[i][2] = __builtin_amdgcn_mfma_f32_16x16x32_bf16(af[i], b0, acc[i][2], 0, 0, 0);
            acc[i][3] = __builtin_amdgcn_mfma_f32_16x16x32_bf16(af[i], b1, acc[i][3], 0, 0, 0);
        }
        __builtin_amdgcn_s_setprio(0);
        __builtin_amdgcn_s_barrier();
        // ---- phase 2: khalf 1, j={0,1} ----
#pragma unroll
        for (int i = 0; i < 8; i++) af[i] = AFRD(1, i);
        b0 = BFRD(1, 0); b1 = BFRD(1, 1);
        __builtin_amdgcn_s_setprio(1);
#pragma unroll
        for (int i = 0; i < 8; i++) {
            acc[i][0] = __builtin_amdgcn_mfma_f32_16x16x32_bf16(af[i], b0, acc[i][0], 0, 0, 0);
            acc[i][1] = __builtin_amdgcn_mfma_f32_16x16x32_bf16(af[i], b1, acc[i][1], 0, 0, 0);
        }
        __builtin_amdgcn_s_setprio(0);
        __builtin_amdgcn_s_barrier();
        // ---- phase 3: khalf 1, j={2,3}; boundary sync (drains stage vmcnt) ----
        b0 = BFRD(1, 2); b1 = BFRD(1, 3);
        __builtin_amdgcn_s_setprio(1);
#pragma unroll
        for (int i = 0; i < 8; i++) {
            acc[i][2] = __builtin_amdgcn_mfma_f32_16x16x32_bf16(af[i], b0, acc[i][2], 0, 0, 0);
            acc[i][3] = __builtin_amdgcn_mfma_f32_16x16x32_bf16(af[i], b1, acc[i][3], 0, 0, 0);
        }
        __builtin_amdgcn_s_setprio(0);
        __syncthreads();                               // reads done + tile t+1 visible
        cur ^= 1;
    }
#undef STAGE256
#undef AFRD
#undef BFRD

    float bv[4];
    if constexpr (MODE == 1 || MODE == 3) {
#pragma unroll
        for (int j = 0; j < 4; j++) bv[j] = bias[bn + wc * 64 + j * 16 + l16];
    }
#pragma unroll
    for (int i = 0; i < 8; i++) {
        int m = bm + wr * 128 + i * 16 + quad * 4;
#pragma unroll
        for (int j = 0; j < 4; j++) {
            int n = bn + wc * 64 + j * 16 + l16;
#pragma unroll
            for (int r = 0; r < 4; r++) {
                float v = acc[i][j][r];
                long idx = (long)(m + r) * ldo + n;
                if constexpr (MODE == 0) {
                    ((bf16*)outv)[idx] = (bf16)CLAMP(v);
                } else if constexpr (MODE == 1) {
                    v += bv[j]; v = v > 0.f ? v : 0.f;
                    ((bf16*)outv)[idx] = (bf16)CLAMP(v);
                } else if constexpr (MODE == 2) {
                    ((float*)outv)[idx] = CLAMP(v + resid[idx]);
                } else if constexpr (MODE == 3) {
                    ((float*)outv)[idx] = CLAMP(v + bv[j] + resid[idx]);
                } else {   // MODE 4
                    ((float*)outv)[idx] += CLAMP(v);
                }
            }
        }
    }
}

// ---------------- MFMA causal flash attention, S^T formulation, DIAGONAL-PAIRED ----------------
#define SM_C 0.1803368801111f   // 0.125 * log2(e)

static __device__ __forceinline__ void attn_tile(
    const bf16x8 kf[4][2], const bf16* sVt, int t0, int qpb,
    int quad, int l16,
    const bf16x8 qf[2][2], f32x4 o[2][4], float* m_i, float* l_i)
{
    if (t0 > qpb + 31) return;    // whole wave-tile causally masked
    bf16x4 pb[2][4];
#pragma unroll
    for (int rf = 0; rf < 2; rf++) {
        f32x4 sc[4];
#pragma unroll
        for (int tt = 0; tt < 4; tt++) {
            f32x4 s4 = f32x4{0.f, 0.f, 0.f, 0.f};
            s4 = __builtin_amdgcn_mfma_f32_16x16x32_bf16(kf[tt][0], qf[rf][0], s4, 0, 0, 0);
            s4 = __builtin_amdgcn_mfma_f32_16x16x32_bf16(kf[tt][1], qf[rf][1], s4, 0, 0, 0);
            sc[tt] = s4;
        }
        const int qpos = qpb + rf * 16 + l16;
        if (t0 + 63 > qpb + rf * 16) {            // boundary tile: mask (wave-uniform branch)
#pragma unroll
            for (int tt = 0; tt < 4; tt++)
#pragma unroll
                for (int r = 0; r < 4; r++) {
                    int tcol = t0 + tt * 16 + quad * 4 + r;
                    float v = sc[tt][r] * SM_C;
                    sc[tt][r] = (tcol > qpos) ? NEGINF : v;
                }
        } else {                                   // interior tile: no mask VALU
#pragma unroll
            for (int tt = 0; tt < 4; tt++)
#pragma unroll
                for (int r = 0; r < 4; r++) sc[tt][r] = sc[tt][r] * SM_C;
        }
        float t4[4];
#pragma unroll
        for (int tt = 0; tt < 4; tt++)
            t4[tt] = fmaxf(fmaxf(sc[tt][0], sc[tt][1]), fmaxf(sc[tt][2], sc[tt][3]));
        float mt = fmaxf(fmaxf(t4[0], t4[1]), fmaxf(t4[2], t4[3]));
        mt = fmaxf(mt, __shfl_xor(mt, 16));
        mt = fmaxf(mt, __shfl_xor(mt, 32));
        float mn = fmaxf(m_i[rf], mt);
        float alpha = exp2fast(m_i[rf] - mn);
        m_i[rf] = mn;
        float lt4[4];
#pragma unroll
        for (int tt = 0; tt < 4; tt++) {
            float e0 = exp2fast(sc[tt][0] - mn);
            float e1 = exp2fast(sc[tt][1] - mn);
            float e2 = exp2fast(sc[tt][2] - mn);
            float e3 = exp2fast(sc[tt][3] - mn);
            sc[tt][0] = e0; sc[tt][1] = e1; sc[tt][2] = e2; sc[tt][3] = e3;
            lt4[tt] = (e0 + e1) + (e2 + e3);
        }
        float lt = (lt4[0] + lt4[1]) + (lt4[2] + lt4[3]);
        lt += __shfl_xor(lt, 16);
        lt += __shfl_xor(lt, 32);
        l_i[rf] = l_i[rf] * alpha + lt;
#pragma unroll
        for (int jb = 0; jb < 4; jb++)
#pragma unroll
            for (int r = 0; r < 4; r++) o[rf][jb][r] *= alpha;
#pragma unroll
        for (int tt = 0; tt < 4; tt++)
            pb[rf][tt] = bf16x4{(bf16)sc[tt][0], (bf16)sc[tt][1], (bf16)sc[tt][2], (bf16)sc[tt][3]};
    }
    // PV: O^T += V^T . P^T  (16x16x16, K-accumulate over tt)
#pragma unroll
    for (int jb = 0; jb < 4; jb++) {
#pragma unroll
        for (int tt = 0; tt < 4; tt++) {
            bf16x4 va = *(const bf16x4*)(&sVt[(jb * 16 + l16) * 72 + tt * 16 + quad * 4]);
            o[0][jb] = mfma16(va, pb[0][tt], o[0][jb]);
            o[1][jb] = mfma16(va, pb[1][tt], o[1][jb]);
        }
    }
}

__global__ __launch_bounds__(256, 2)
void attn_kernel(const bf16* __restrict__ qkv, const bf16* __restrict__ Vt, bf16* __restrict__ ctx)
{
    const int bh = blockIdx.x;
    const int p  = blockIdx.y;            // diagonal pair 0..7
    const int b = bh >> 4, h = bh & 15;
    const int t = threadIdx.x;
    const int wave = t >> 6, lane = t & 63;
    const int quad = lane >> 4, l16 = lane & 15;
    const long RS = 3072;
    const int qb0 = p, qb1 = 15 - p;
    const int nt0 = 2 * p + 2, nt1 = 32 - 2 * p;

    __shared__ bf16 sK[64 * 72];      // [t][d]
    __shared__ bf16 sVt[64 * 72];     // [d][t]

    bf16x8 qf[2][2][2];
#pragma unroll
    for (int s = 0; s < 2; s++) {
        const int qb = s ? qb1 : qb0;
#pragma unroll
        for (int rf = 0; rf < 2; rf++) {
            const bf16* qp = qkv + (long)(b * 2048 + qb * 128 + wave * 32 + rf * 16 + l16) * RS + h * 64 + quad * 8;
            qf[s][rf][0] = *(const bf16x8*)(qp);
            qf[s][rf][1] = *(const bf16x8*)(qp + 32);
        }
    }
    f32x4 o[2][2][4];                  // [s][rf][jb]
#pragma unroll
    for (int s = 0; s < 2; s++)
#pragma unroll
        for (int rf = 0; rf < 2; rf++)
#pragma unroll
            for (int jb = 0; jb < 4; jb++) o[s][rf][jb] = f32x4{0.f, 0.f, 0.f, 0.f};
    float m_i[2][2] = {{NEGINF, NEGINF}, {NEGINF, NEGINF}};
    float l_i[2][2] = {{0.f, 0.f}, {0.f, 0.f}};
    const int qpb0 = qb0 * 128 + wave * 32;
    const int qpb1 = qb1 * 128 + wave * 32;

    const int cg = (t & 7) * 8, rr = t >> 3;
    const bf16* Kbase  = qkv + (long)(b * 2048) * RS + 1024 + h * 64;
    const bf16* Vtbase = Vt + ((long)bh * 64) * 2048;

    bf16x8 kreg[2], vreg[2];
#pragma unroll
    for (int pp = 0; pp < 2; pp++) {   // prefetch tile 0
        kreg[pp] = *(const bf16x8*)(Kbase + (long)(pp * 32 + rr) * RS + cg);
        vreg[pp] = *(const bf16x8*)(Vtbase + (long)(pp * 32 + rr) * 2048 + cg);
    }

    for (int ti = 0; ti < nt1; ti++) {
        __syncthreads();
#pragma unroll
        for (int pp = 0; pp < 2; pp++) {
            *(bf16x8*)(&sK[(pp * 32 + rr) * 72 + cg]) = kreg[pp];
            *(bf16x8*)(&sVt[(pp * 32 + rr) * 72 + cg]) = vreg[pp];
        }
        __syncthreads();
        if (ti + 1 < nt1) {
            int t0n = (ti + 1) * 64;
#pragma unroll
            for (int pp = 0; pp < 2; pp++) {
                kreg[pp] = *(const bf16x8*)(Kbase + (long)(t0n + pp * 32 + rr) * RS + cg);
                vreg[pp] = *(const bf16x8*)(Vtbase + (long)(pp * 32 + rr) * 2048 + t0n + cg);
            }
        }
        const int t0 = ti * 64;

        bf16x8 kf[4][2];
#pragma unroll
        for (int tt = 0; tt < 4; tt++) {
            kf[tt][0] = *(const bf16x8*)(&sK[(tt * 16 + l16) * 72 + quad * 8]);
            kf[tt][1] = *(const bf16x8*)(&sK[(tt * 16 + l16) * 72 + 32 + quad * 8]);
        }
        if (ti < nt0)
            attn_tile(kf, sVt, t0, qpb0, quad, l16, qf[0], o[0], m_i[0], l_i[0]);
        attn_tile(kf, sVt, t0, qpb1, quad, l16, qf[1], o[1], m_i[1], l_i[1]);
    }
#pragma unroll
    for (int s = 0; s < 2; s++) {
        const int qpb = s ? qpb1 : qpb0;
#pragma unroll
        for (int rf = 0; rf < 2; rf++) {
            float rl = 1.0f / l_i[s][rf];
            const long row = (long)(b * 2048 + qpb + rf * 16 + l16) * 1024 + h * 64;
#pragma unroll
            for (int jb = 0; jb < 4; jb++) {
                bf16x4 ov;
#pragma unroll
                for (int r = 0; r < 4; r++) ov[r] = (bf16)CLAMP(o[s][rf][jb][r] * rl);
                *(bf16x4*)(&ctx[row + jb * 16 + quad * 4]) = ov;
            }
        }
    }
}

// ---------------- confidence head (f32) ----------------
__global__ __launch_bounds__(256)
void conf_partial(const float* __restrict__ xout, const float* __restrict__ cw, float* __restrict__ part)
{
    int blk = blockIdx.x;
    int b = blk >> 6, chunk = blk & 63;
    int t = threadIdx.x;
    int d0 = t * 4;
    f32x4 w = *(const f32x4*)(cw + d0);
    float acc = 0.f;
    for (int s = chunk * 32; s < chunk * 32 + 32; s++) {
        f32x4 v = *(const f32x4*)(xout + (long)(b * 2048 + s) * 1024 + d0);
        acc += v[0] * w[0] + v[1] * w[1] + v[2] * w[2] + v[3] * w[3];
    }
#pragma unroll
    for (int off = 32; off; off >>= 1) acc += __shfl_xor(acc, off);
    __shared__ float ls[4];
    if ((t & 63) == 0) ls[t >> 6] = acc;
    __syncthreads();
    if (t == 0) part[blk] = ls[0] + ls[1] + ls[2] + ls[3];
}

__global__ void conf_final(const float* __restrict__ part, const float* __restrict__ cb, float* __restrict__ outp)
{
    if (threadIdx.x == 0) {
        float accb = 0.f;
        for (int b = 0; b < 4; b++) {
            float s = 0.f;
            for (int i = 0; i < 64; i++) s += part[b * 64 + i];
            float z = s / 2048.0f + cb[0];
            accb += 1.0f / (1.0f + expf(-z));
        }
        outp[0] = accb * 0.25f;
    }
}

// ---------------- launch ----------------
// Workspace (1 MB = 1<<20), peak 96 MB + 1 KB, phase-disjoint aliasing:
//  [ 0, 8): WqkvT (ph1-3) -> W1T (ph6+)
//  [ 8,16): WoT (ph1-5)   -> W2T (ph6+)
//  [16,32): h (ph2-3) -> ctx (ph4-5) -> h2 (ph7-9)
//  [32,80): qkv (ph3-4); x1 f32 [32,64) ph5+ (qkv dead)
//  [80,96): Vt (ph3.5-4); a1h [64,96) ph8-9 (qkv tail + Vt dead)
//  [96MB):  part f32[256]
extern "C" void kernel_launch(void* const* d_in, const int* in_sizes, int n_in,
                              void* d_out, int out_size, void* d_ws, size_t ws_size,
                              hipStream_t stream)
{
    const int D = 1024, F = 4096, M = 8192;
    const size_t MB = 1u << 20;
    const float* x     = (const float*)d_in[0];
    const float* Wq    = (const float*)d_in[1];
    const float* Wk    = (const float*)d_in[2];
    const float* Wv    = (const float*)d_in[3];
    const float* Wo    = (const float*)d_in[4];
    const float* ln1w  = (const float*)d_in[5];
    const float* ln1b  = (const float*)d_in[6];
    const float* W1    = (const float*)d_in[7];
    const float* b1    = (const float*)d_in[8];
    const float* W2    = (const float*)d_in[9];
    const float* b2    = (const float*)d_in[10];
    const float* ln2w  = (const float*)d_in[11];
    const float* ln2b  = (const float*)d_in[12];
    const float* confw = (const float*)d_in[13];
    const float* confb = (const float*)d_in[14];
    float* out = (float*)d_out;

    char* ws = (char*)d_ws;
    bf16*  WqkvT = (bf16*)(ws);
    bf16*  WoT   = (bf16*)(ws + 8 * MB);
    bf16*  h     = (bf16*)(ws + 16 * MB);
    bf16*  qkv   = (bf16*)(ws + 32 * MB);
    bf16*  Vt    = (bf16*)(ws + 80 * MB);
    bf16*  ctx   = (bf16*)(ws + 16 * MB);
    float* x1    = (float*)(ws + 32 * MB);
    bf16*  h2    = (bf16*)(ws + 16 * MB);
    bf16*  W1T   = (bf16*)(ws);
    bf16*  W2T   = (bf16*)(ws + 8 * MB);
    bf16*  a1h   = (bf16*)(ws + 64 * MB);
    float* part  = (float*)(ws + 96 * MB);

    dim3 tb(32, 8);
    // ph1: QKV/Wo weight transposes in one launch
    transpose4_kernel<<<dim3(32, 32, 4), tb, 0, stream>>>(Wq, Wk, Wv, Wo, WqkvT, WoT);
    // ph2: LN1
    ln_kernel<<<M, 256, 0, stream>>>(x, ln1w, ln1b, h);
    // ph3: QKV projection (256^2 tile: 384 blocks)
    gemm256<0><<<dim3(12, 32), 512, 0, stream>>>(h, D, WqkvT, D, M, 3 * D, D, nullptr, nullptr, qkv, 3 * D);
    // ph3.5: V transpose
    v_transpose<<<dim3(64, 2, 64), tb, 0, stream>>>(qkv, Vt);
    // ph4: attention (diagonal-paired: 512 uniform blocks, fully co-resident)
    attn_kernel<<<dim3(64, 8), 256, 0, stream>>>(qkv, Vt, ctx);
    // ph5: Wo projection + residual -> x1 f32 (128^2: 512 blocks)
    gemm_bt<2><<<dim3(8, 64), 256, 0, stream>>>(ctx, D, WoT, D, M, D, D, nullptr, x, x1, D);
    // ph6: FFN weight transposes
    transpose_kernel<<<dim3(F / 32, D / 32), tb, 0, stream>>>(W1, W1T, D, F);
    transpose_kernel<<<dim3(D / 32, F / 32), tb, 0, stream>>>(W2, W2T, F, D);
    // ph7: LN2
    ln_kernel<<<M, 256, 0, stream>>>(x1, ln2w, ln2b, h2);
    // ph8: FFN half 1 (inner 256^2: 256 blocks; outer 128^2 k-split accumulate)
    gemm256<1><<<dim3(8, 32), 512, 0, stream>>>(h2, D, W1T, D, M, 2048, D, b1, nullptr, a1h, 2048);
    gemm_bt<4><<<dim3(8, 64), 256, 0, stream>>>(a1h, 2048, W2T, F, M, D, 2048, nullptr, nullptr, x1, D);
    // ph9: FFN half 2 -> out f32
    gemm256<1><<<dim3(8, 32), 512, 0, stream>>>(h2, D, W1T + (size_t)2048 * D, D, M, 2048, D, b1 + 2048, nullptr, a1h, 2048);
    gemm_bt<3><<<dim3(8, 64), 256, 0, stream>>>(a1h, 2048, W2T + 2048, F, M, D, 2048, b2, x1, out, D);
    // ph10: confidence head
    conf_partial<<<256, 256, 0, stream>>>(out, confw, part);
    conf_final<<<1, 64, 0, stream>>>(part, confb, out + (size_t)M * D);
}

// Round 11
// 533.954 us; speedup vs baseline: 1.1014x; 1.0100x over previous
//
#include <hip/hip_runtime.h>
#include <hip/hip_bf16.h>
#include <math.h>

typedef __bf16 bf16;
typedef __bf16 bf16x8 __attribute__((ext_vector_type(8)));
typedef __bf16 bf16x4 __attribute__((ext_vector_type(4)));
typedef float  f32x4  __attribute__((ext_vector_type(4)));
typedef short  s16x4  __attribute__((ext_vector_type(4)));

#define CLAMP(v) fminf(fmaxf((v), -100.f), 100.f)   // NaN tripwire; legit |v| <= ~40
#define NEGINF (-1e30f)
#define SM_C 0.1803368801111f   // 0.125 * log2(e) — folded into Q at QKV epilogue

// native 2^x (v_exp_f32). __exp2f collides with glibc macros; use the amdgcn builtin.
static __device__ __forceinline__ float exp2fast(float x)
{
#if __has_builtin(__builtin_amdgcn_exp2f)
    return __builtin_amdgcn_exp2f(x);
#else
    return exp2f(x);
#endif
}

// K=16 bf16 MFMA (PV stage): builtin name differs across ROCm versions
static __device__ __forceinline__ f32x4 mfma16(bf16x4 a, bf16x4 b, f32x4 c)
{
#if __has_builtin(__builtin_amdgcn_mfma_f32_16x16x16_bf16)
    return __builtin_amdgcn_mfma_f32_16x16x16_bf16(a, b, c, 0, 0, 0);
#else
    s16x4 as, bs;
    __builtin_memcpy(&as, &a, 8);
    __builtin_memcpy(&bs, &b, 8);
    return __builtin_amdgcn_mfma_f32_16x16x16bf16_1k(as, bs, c, 0, 0, 0);
#endif
}

// async global -> LDS, 16B per lane. LDS dest is wave-uniform base + lane*16;
// global src is per-lane. (learn_hip m97 pattern)
static __device__ __forceinline__ void gload_lds16(const bf16* g, bf16* l)
{
    __builtin_amdgcn_global_load_lds(
        (const __attribute__((address_space(1))) void*)g,
        (__attribute__((address_space(3))) void*)l, 16, 0, 0);
}

// XCD-aware bijective block swizzle (T1, m157/m204): requires nwg % 8 == 0.
static __device__ __forceinline__ void xcd_swizzle(int& bx, int& by)
{
    int gx = gridDim.x, nwg = gx * gridDim.y;
    int lin = by * gx + bx;
    int cpx = nwg >> 3;
    int swz = (lin & 7) * cpx + (lin >> 3);
    bx = swz % gx;
    by = swz / gx;
}

// ---------------- 4x weight transpose + cast: dst_bf16[C][R] = src_f32[R][C], D x D ----------------
__global__ __launch_bounds__(256)
void transpose4_kernel(const float* __restrict__ Wq, const float* __restrict__ Wk,
                       const float* __restrict__ Wv, const float* __restrict__ Wo,
                       bf16* __restrict__ dstQKV, bf16* __restrict__ dstO)
{
    const int D = 1024;
    const float* src = (blockIdx.z == 0) ? Wq : (blockIdx.z == 1) ? Wk : (blockIdx.z == 2) ? Wv : Wo;
    bf16* dst = (blockIdx.z < 3) ? dstQKV + (size_t)blockIdx.z * D * D : dstO;
    __shared__ float tile[32][33];
    int c0 = blockIdx.x * 32, r0 = blockIdx.y * 32;
    int tx = threadIdx.x, ty = threadIdx.y;   // block (32,8)
#pragma unroll
    for (int i = 0; i < 4; i++)
        tile[ty + i * 8][tx] = src[(long)(r0 + ty + i * 8) * D + c0 + tx];
    __syncthreads();
#pragma unroll
    for (int i = 0; i < 4; i++)
        dst[(long)(c0 + ty + i * 8) * D + r0 + tx] = (bf16)tile[tx][ty + i * 8];
}

// ---------------- generic weight transpose + cast (W1/W2) ----------------
__global__ __launch_bounds__(256)
void transpose_kernel(const float* __restrict__ src, bf16* __restrict__ dst, int R, int C)
{
    __shared__ float tile[32][33];
    int c0 = blockIdx.x * 32, r0 = blockIdx.y * 32;
    int tx = threadIdx.x, ty = threadIdx.y;
#pragma unroll
    for (int i = 0; i < 4; i++)
        tile[ty + i * 8][tx] = src[(long)(r0 + ty + i * 8) * C + c0 + tx];
    __syncthreads();
#pragma unroll
    for (int i = 0; i < 4; i++)
        dst[(long)(c0 + ty + i * 8) * R + r0 + tx] = (bf16)tile[tx][ty + i * 8];
}

// ---------------- V transpose: Vt[bh][d][t] = qkv[(b*2048+t)*3072 + 2048 + h*64 + d] ----------------
__global__ __launch_bounds__(256)
void v_transpose(const bf16* __restrict__ qkv, bf16* __restrict__ Vt)
{
    __shared__ bf16 tile[32][33];
    int bh = blockIdx.z, b = bh >> 4, h = bh & 15;
    int t0 = blockIdx.x * 32, d0 = blockIdx.y * 32;
    int tx = threadIdx.x, ty = threadIdx.y;
#pragma unroll
    for (int i = 0; i < 4; i++)
        tile[ty + i * 8][tx] = qkv[(long)(b * 2048 + t0 + ty + i * 8) * 3072 + 2048 + h * 64 + d0 + tx];
    __syncthreads();
#pragma unroll
    for (int i = 0; i < 4; i++)
        Vt[((long)bh * 64 + d0 + ty + i * 8) * 2048 + t0 + tx] = tile[tx][ty + i * 8];
}

// ---------------- layernorm (row per block, D=1024, 256 thr), f32 in -> bf16 out ----------------
__global__ __launch_bounds__(256)
void ln_kernel(const float* __restrict__ x, const float* __restrict__ w, const float* __restrict__ b,
               bf16* __restrict__ out)
{
    const int D = 1024;
    const long row = blockIdx.x;
    const int t = threadIdx.x;
    f32x4 xv = *(const f32x4*)(x + row * D + t * 4);
    float s  = xv[0] + xv[1] + xv[2] + xv[3];
    float s2 = xv[0] * xv[0] + xv[1] * xv[1] + xv[2] * xv[2] + xv[3] * xv[3];
#pragma unroll
    for (int off = 32; off; off >>= 1) { s += __shfl_xor(s, off); s2 += __shfl_xor(s2, off); }
    __shared__ float ls[4], ls2[4];
    if ((t & 63) == 0) { ls[t >> 6] = s; ls2[t >> 6] = s2; }
    __syncthreads();
    s = ls[0] + ls[1] + ls[2] + ls[3];
    s2 = ls2[0] + ls2[1] + ls2[2] + ls2[3];
    float mu = s / D;
    float var = fmaxf(s2 / D - mu * mu, 0.f);
    float rstd = rsqrtf(var + 1e-5f);
#pragma unroll
    for (int i = 0; i < 4; i++) {
        int c = t * 4 + i;
        float v = (xv[i] - mu) * rstd * w[c] + b[c];
        out[row * D + c] = (bf16)CLAMP(v);
    }
}

// ---------------- GEMM 128x128 tile (Wo, FFN2), BK=64 (2x BK32 subtiles), dbuf ----------------
// MODE 0: out bf16 = clamp(acc)                               (qkv)
// MODE 1: out bf16 = clamp(relu(acc + bias_f32[n]))           (FFN inner)
// MODE 2: out f32  = clamp(acc + resid_f32[m,n])              (x1 = ctx@Wo + x)
// MODE 3: out f32  = clamp(acc + bias_f32[n] + resid_f32[m,n])(final out)
// MODE 4: out f32 += clamp(acc)                               (k-split accumulate)
template <int MODE>
__global__ __launch_bounds__(256)
void gemm_bt(const bf16* __restrict__ A, int lda, const bf16* __restrict__ Bt, int ldb,
             int M, int N, int K,
             const float* __restrict__ bias, const float* __restrict__ resid,
             void* __restrict__ outv, int ldo)
{
    __shared__ bf16 sA[2][2][128 * 32];   // [buf][khalf][row*32+col] — 32 KB
    __shared__ bf16 sB[2][2][128 * 32];   // 32 KB
    const int t = threadIdx.x;
    const int wave = t >> 6, lane = t & 63;
    const int wr = wave >> 1, wc = wave & 1;      // 2x2 wave grid, 64x64 per wave
    const int quad = lane >> 4, l16 = lane & 15;
    int bx = blockIdx.x, by = blockIdx.y;
    xcd_swizzle(bx, by);
    const int bm = by * 128, bn = bx * 128;

    f32x4 acc[4][4];
#pragma unroll
    for (int i = 0; i < 4; i++)
#pragma unroll
        for (int j = 0; j < 4; j++) acc[i][j] = f32x4{0.f, 0.f, 0.f, 0.f};

    const int srow = wave * 16 + (lane >> 2);     // global row within tile
    const int scol = (lane & 3) * 8;              // halfword col group (16B)
    const bf16* ga = A + (long)(bm + srow) * lda + scol;
    const bf16* gb = Bt + (long)(bn + srow) * ldb + scol;
    const int lbase = wave * 16 * 32;             // wave-uniform LDS base (halfwords)

#define STAGE128(buf, k0)                                                          \
    do {                                                                           \
        gload_lds16(ga + (k0), &sA[buf][0][lbase]);                                \
        gload_lds16(gb + (k0), &sB[buf][0][lbase]);                                \
        gload_lds16(ga + (long)64 * lda + (k0), &sA[buf][0][lbase + 64 * 32]);     \
        gload_lds16(gb + (long)64 * ldb + (k0), &sB[buf][0][lbase + 64 * 32]);     \
        gload_lds16(ga + (k0) + 32, &sA[buf][1][lbase]);                           \
        gload_lds16(gb + (k0) + 32, &sB[buf][1][lbase]);                           \
        gload_lds16(ga + (long)64 * lda + (k0) + 32, &sA[buf][1][lbase + 64 * 32]);\
        gload_lds16(gb + (long)64 * ldb + (k0) + 32, &sB[buf][1][lbase + 64 * 32]);\
    } while (0)

    STAGE128(0, 0);
    __syncthreads();
    int cur = 0;
    for (int k0 = 0; k0 < K; k0 += 64) {
        if (k0 + 64 < K) STAGE128(cur ^ 1, k0 + 64);   // prefetch next 64-K tile
#pragma unroll
        for (int kh = 0; kh < 2; kh++) {
            bf16x8 af[4], bfv[4];
#pragma unroll
            for (int i = 0; i < 4; i++)
                af[i] = *(const bf16x8*)(&sA[cur][kh][(wr * 64 + i * 16 + l16) * 32 + quad * 8]);
#pragma unroll
            for (int j = 0; j < 4; j++)
                bfv[j] = *(const bf16x8*)(&sB[cur][kh][(wc * 64 + j * 16 + l16) * 32 + quad * 8]);
#pragma unroll
            for (int i = 0; i < 4; i++)
#pragma unroll
                for (int j = 0; j < 4; j++)
                    acc[i][j] = __builtin_amdgcn_mfma_f32_16x16x32_bf16(af[i], bfv[j], acc[i][j], 0, 0, 0);
        }
        __syncthreads();                               // drains prefetch vmcnt + read sync
        cur ^= 1;
    }
#undef STAGE128

    float bv[4];
    if constexpr (MODE == 1 || MODE == 3) {
#pragma unroll
        for (int j = 0; j < 4; j++) bv[j] = bias[bn + wc * 64 + j * 16 + l16];
    }
#pragma unroll
    for (int i = 0; i < 4; i++) {
        int m = bm + wr * 64 + i * 16 + quad * 4;
#pragma unroll
        for (int j = 0; j < 4; j++) {
            int n = bn + wc * 64 + j * 16 + l16;
#pragma unroll
            for (int r = 0; r < 4; r++) {
                float v = acc[i][j][r];
                long idx = (long)(m + r) * ldo + n;
                if constexpr (MODE == 0) {
                    ((bf16*)outv)[idx] = (bf16)CLAMP(v);
                } else if constexpr (MODE == 1) {
                    v += bv[j]; v = v > 0.f ? v : 0.f;
                    ((bf16*)outv)[idx] = (bf16)CLAMP(v);
                } else if constexpr (MODE == 2) {
                    ((float*)outv)[idx] = CLAMP(v + resid[idx]);
                } else if constexpr (MODE == 3) {
                    ((float*)outv)[idx] = CLAMP(v + bv[j] + resid[idx]);
                } else {   // MODE 4
                    ((float*)outv)[idx] += CLAMP(v);
                }
            }
        }
    }
}

// ---------------- GEMM 256x256 tile (QKV, FFN1), BK=64, 4-PHASE interleave ----------------
// MODE 0 additionally pre-scales the Q third (bn < 1024) by SM_C so attention's QK^T
// lands directly in exp2 domain (removes 64 VALU mults/tile/wave in attn softmax).
// Tile cols are 256-aligned -> the bn<1024 test is block-uniform, zero epilogue cost.
template <int MODE>
__global__ __launch_bounds__(512, 1)
void gemm256(const bf16* __restrict__ A, int lda, const bf16* __restrict__ Bt, int ldb,
             int M, int N, int K,
             const float* __restrict__ bias, const float* __restrict__ resid,
             void* __restrict__ outv, int ldo)
{
    __shared__ bf16 sA[2][2][256 * 32];   // [buf][khalf][...] — 64 KB
    __shared__ bf16 sB[2][2][256 * 32];   // 64 KB
    const int t = threadIdx.x;
    const int wave = t >> 6, lane = t & 63;
    const int wr = wave >> 2, wc = wave & 3;      // 2x4 wave grid, 128x64 per wave
    const int quad = lane >> 4, l16 = lane & 15;
    int bx = blockIdx.x, by = blockIdx.y;
    xcd_swizzle(bx, by);
    const int bm = by * 256, bn = bx * 256;

    f32x4 acc[8][4];
#pragma unroll
    for (int i = 0; i < 8; i++)
#pragma unroll
        for (int j = 0; j < 4; j++) acc[i][j] = f32x4{0.f, 0.f, 0.f, 0.f};

    // staging: 512 threads cover 128 rows per call (row = t>>2, colgroup = (t&3)*8)
    const int srow = t >> 2;
    const int scol = (t & 3) * 8;
    const bf16* ga = A + (long)(bm + srow) * lda + scol;
    const bf16* gb = Bt + (long)(bn + srow) * ldb + scol;
    const int lbase = wave * 16 * 32;             // wave-uniform LDS base (lane*16B contiguous)

#define STAGE256(buf, k0)                                                            \
    do {                                                                             \
        gload_lds16(ga + (k0), &sA[buf][0][lbase]);                                  \
        gload_lds16(gb + (k0), &sB[buf][0][lbase]);                                  \
        gload_lds16(ga + (long)128 * lda + (k0), &sA[buf][0][lbase + 128 * 32]);     \
        gload_lds16(gb + (long)128 * ldb + (k0), &sB[buf][0][lbase + 128 * 32]);     \
        gload_lds16(ga + (k0) + 32, &sA[buf][1][lbase]);                             \
        gload_lds16(gb + (k0) + 32, &sB[buf][1][lbase]);                             \
        gload_lds16(ga + (long)128 * lda + (k0) + 32, &sA[buf][1][lbase + 128 * 32]);\
        gload_lds16(gb + (long)128 * ldb + (k0) + 32, &sB[buf][1][lbase + 128 * 32]);\
    } while (0)

    // fragment read helpers (conflict-floor [row][32] layout)
#define AFRD(kh, i) (*(const bf16x8*)(&sA[cur][kh][(wr * 128 + (i) * 16 + l16) * 32 + quad * 8]))
#define BFRD(kh, j) (*(const bf16x8*)(&sB[cur][kh][(wc * 64 + (j) * 16 + l16) * 32 + quad * 8]))

    STAGE256(0, 0);
    __syncthreads();                                   // prologue: tile 0 landed
    int cur = 0;
    for (int k0 = 0; k0 < K; k0 += 64) {
        const int nxt = cur ^ 1;
        bf16x8 af[8], b0, b1;
        // ---- phase 0: khalf 0, j={0,1}; issue all stages for tile t+1 -> nxt ----
#pragma unroll
        for (int i = 0; i < 8; i++) af[i] = AFRD(0, i);
        b0 = BFRD(0, 0); b1 = BFRD(0, 1);
        if (k0 + 64 < K) STAGE256(nxt, k0 + 64);
        __builtin_amdgcn_s_setprio(1);
#pragma unroll
        for (int i = 0; i < 8; i++) {
            acc[i][0] = __builtin_amdgcn_mfma_f32_16x16x32_bf16(af[i], b0, acc[i][0], 0, 0, 0);
            acc[i][1] = __builtin_amdgcn_mfma_f32_16x16x32_bf16(af[i], b1, acc[i][1], 0, 0, 0);
        }
        __builtin_amdgcn_s_setprio(0);
        __builtin_amdgcn_s_barrier();
        // ---- phase 1: khalf 0, j={2,3} ----
        b0 = BFRD(0, 2); b1 = BFRD(0, 3);
        __builtin_amdgcn_s_setprio(1);
#pragma unroll
        for (int i = 0; i < 8; i++) {
            acc[i][2] = __builtin_amdgcn_mfma_f32_16x16x32_bf16(af[i], b0, acc[i][2], 0, 0, 0);
            acc[i][3] = __builtin_amdgcn_mfma_f32_16x16x32_bf16(af[i], b1, acc[i][3], 0, 0, 0);
        }
        __builtin_amdgcn_s_setprio(0);
        __builtin_amdgcn_s_barrier();
        // ---- phase 2: khalf 1, j={0,1} ----
#pragma unroll
        for (int i = 0; i < 8; i++) af[i] = AFRD(1, i);
        b0 = BFRD(1, 0); b1 = BFRD(1, 1);
        __builtin_amdgcn_s_setprio(1);
#pragma unroll
        for (int i = 0; i < 8; i++) {
            acc[i][0] = __builtin_amdgcn_mfma_f32_16x16x32_bf16(af[i], b0, acc[i][0], 0, 0, 0);
            acc[i][1] = __builtin_amdgcn_mfma_f32_16x16x32_bf16(af[i], b1, acc[i][1], 0, 0, 0);
        }
        __builtin_amdgcn_s_setprio(0);
        __builtin_amdgcn_s_barrier();
        // ---- phase 3: khalf 1, j={2,3}; boundary sync (drains stage vmcnt) ----
        b0 = BFRD(1, 2); b1 = BFRD(1, 3);
        __builtin_amdgcn_s_setprio(1);
#pragma unroll
        for (int i = 0; i < 8; i++) {
            acc[i][2] = __builtin_amdgcn_mfma_f32_16x16x32_bf16(af[i], b0, acc[i][2], 0, 0, 0);
            acc[i][3] = __builtin_amdgcn_mfma_f32_16x16x32_bf16(af[i], b1, acc[i][3], 0, 0, 0);
        }
        __builtin_amdgcn_s_setprio(0);
        __syncthreads();                               // reads done + tile t+1 visible
        cur ^= 1;
    }
#undef STAGE256
#undef AFRD
#undef BFRD

    float bv[4];
    if constexpr (MODE == 1 || MODE == 3) {
#pragma unroll
        for (int j = 0; j < 4; j++) bv[j] = bias[bn + wc * 64 + j * 16 + l16];
    }
    const float oscale = (MODE == 0 && bn < 1024) ? SM_C : 1.0f;   // Q pre-scale (block-uniform)
#pragma unroll
    for (int i = 0; i < 8; i++) {
        int m = bm + wr * 128 + i * 16 + quad * 4;
#pragma unroll
        for (int j = 0; j < 4; j++) {
            int n = bn + wc * 64 + j * 16 + l16;
#pragma unroll
            for (int r = 0; r < 4; r++) {
                float v = acc[i][j][r];
                long idx = (long)(m + r) * ldo + n;
                if constexpr (MODE == 0) {
                    ((bf16*)outv)[idx] = (bf16)CLAMP(v * oscale);
                } else if constexpr (MODE == 1) {
                    v += bv[j]; v = v > 0.f ? v : 0.f;
                    ((bf16*)outv)[idx] = (bf16)CLAMP(v);
                } else if constexpr (MODE == 2) {
                    ((float*)outv)[idx] = CLAMP(v + resid[idx]);
                } else if constexpr (MODE == 3) {
                    ((float*)outv)[idx] = CLAMP(v + bv[j] + resid[idx]);
                } else {   // MODE 4
                    ((float*)outv)[idx] += CLAMP(v);
                }
            }
        }
    }
}

// ---------------- MFMA causal flash attention, S^T formulation, DIAGONAL-PAIRED ----------------
// Q is pre-scaled by SM_C at the QKV GEMM -> QK^T already in exp2 domain (no per-element
// scale here). Defer-max (T13): skip {mn, alpha, o/l rescale} when the tile max is within
// 8 of the running max (wave-uniform via __all) — P bounded by 2^8, f32 accum fine.
// Safety: every processed row has >=1 unmasked col (t0 <= qpb <= qpos by construction),
// so mt is finite; first tile (m_i = -inf) always takes the full path.
static __device__ __forceinline__ void attn_tile(
    const bf16x8 kf[4][2], const bf16* sVt, int t0, int qpb,
    int quad, int l16,
    const bf16x8 qf[2][2], f32x4 o[2][4], float* m_i, float* l_i)
{
    if (t0 > qpb + 31) return;    // whole wave-tile causally masked
    bf16x4 pb[2][4];
#pragma unroll
    for (int rf = 0; rf < 2; rf++) {
        f32x4 sc[4];
#pragma unroll
        for (int tt = 0; tt < 4; tt++) {
            f32x4 s4 = f32x4{0.f, 0.f, 0.f, 0.f};
            s4 = __builtin_amdgcn_mfma_f32_16x16x32_bf16(kf[tt][0], qf[rf][0], s4, 0, 0, 0);
            s4 = __builtin_amdgcn_mfma_f32_16x16x32_bf16(kf[tt][1], qf[rf][1], s4, 0, 0, 0);
            sc[tt] = s4;
        }
        const int qpos = qpb + rf * 16 + l16;
        if (t0 + 63 > qpb + rf * 16) {            // boundary tile: mask (wave-uniform branch)
#pragma unroll
            for (int tt = 0; tt < 4; tt++)
#pragma unroll
                for (int r = 0; r < 4; r++) {
                    int tcol = t0 + tt * 16 + quad * 4 + r;
                    sc[tt][r] = (tcol > qpos) ? NEGINF : sc[tt][r];
                }
        }
        float t4[4];
#pragma unroll
        for (int tt = 0; tt < 4; tt++)
            t4[tt] = fmaxf(fmaxf(sc[tt][0], sc[tt][1]), fmaxf(sc[tt][2], sc[tt][3]));
        float mt = fmaxf(fmaxf(t4[0], t4[1]), fmaxf(t4[2], t4[3]));
        mt = fmaxf(mt, __shfl_xor(mt, 16));
        mt = fmaxf(mt, __shfl_xor(mt, 32));
        // defer-max: rescale only when the tile max meaningfully exceeds the running max
        if (!__all(mt <= m_i[rf] + 8.f)) {
            float mn = fmaxf(m_i[rf], mt);
            float alpha = exp2fast(m_i[rf] - mn);
            m_i[rf] = mn;
            l_i[rf] *= alpha;
#pragma unroll
            for (int jb = 0; jb < 4; jb++)
#pragma unroll
                for (int r = 0; r < 4; r++) o[rf][jb][r] *= alpha;
        }
        const float mref = m_i[rf];
        float lt4[4];
#pragma unroll
        for (int tt = 0; tt < 4; tt++) {
            float e0 = exp2fast(sc[tt][0] - mref);
            float e1 = exp2fast(sc[tt][1] - mref);
            float e2 = exp2fast(sc[tt][2] - mref);
            float e3 = exp2fast(sc[tt][3] - mref);
            sc[tt][0] = e0; sc[tt][1] = e1; sc[tt][2] = e2; sc[tt][3] = e3;
            lt4[tt] = (e0 + e1) + (e2 + e3);
        }
        float lt = (lt4[0] + lt4[1]) + (lt4[2] + lt4[3]);
        lt += __shfl_xor(lt, 16);
        lt += __shfl_xor(lt, 32);
        l_i[rf] += lt;
#pragma unroll
        for (int tt = 0; tt < 4; tt++)
            pb[rf][tt] = bf16x4{(bf16)sc[tt][0], (bf16)sc[tt][1], (bf16)sc[tt][2], (bf16)sc[tt][3]};
    }
    // PV: O^T += V^T . P^T  (16x16x16, K-accumulate over tt)
#pragma unroll
    for (int jb = 0; jb < 4; jb++) {
#pragma unroll
        for (int tt = 0; tt < 4; tt++) {
            bf16x4 va = *(const bf16x4*)(&sVt[(jb * 16 + l16) * 72 + tt * 16 + quad * 4]);
            o[0][jb] = mfma16(va, pb[0][tt], o[0][jb]);
            o[1][jb] = mfma16(va, pb[1][tt], o[1][jb]);
        }
    }
}

__global__ __launch_bounds__(256, 2)
void attn_kernel(const bf16* __restrict__ qkv, const bf16* __restrict__ Vt, bf16* __restrict__ ctx)
{
    const int bh = blockIdx.x;
    const int p  = blockIdx.y;            // diagonal pair 0..7
    const int b = bh >> 4, h = bh & 15;
    const int t = threadIdx.x;
    const int wave = t >> 6, lane = t & 63;
    const int quad = lane >> 4, l16 = lane & 15;
    const long RS = 3072;
    const int qb0 = p, qb1 = 15 - p;
    const int nt0 = 2 * p + 2, nt1 = 32 - 2 * p;

    __shared__ bf16 sK[64 * 72];      // [t][d]
    __shared__ bf16 sVt[64 * 72];     // [d][t]

    bf16x8 qf[2][2][2];
#pragma unroll
    for (int s = 0; s < 2; s++) {
        const int qb = s ? qb1 : qb0;
#pragma unroll
        for (int rf = 0; rf < 2; rf++) {
            const bf16* qp = qkv + (long)(b * 2048 + qb * 128 + wave * 32 + rf * 16 + l16) * RS + h * 64 + quad * 8;
            qf[s][rf][0] = *(const bf16x8*)(qp);
            qf[s][rf][1] = *(const bf16x8*)(qp + 32);
        }
    }
    f32x4 o[2][2][4];                  // [s][rf][jb]
#pragma unroll
    for (int s = 0; s < 2; s++)
#pragma unroll
        for (int rf = 0; rf < 2; rf++)
#pragma unroll
            for (int jb = 0; jb < 4; jb++) o[s][rf][jb] = f32x4{0.f, 0.f, 0.f, 0.f};
    float m_i[2][2] = {{NEGINF, NEGINF}, {NEGINF, NEGINF}};
    float l_i[2][2] = {{0.f, 0.f}, {0.f, 0.f}};
    const int qpb0 = qb0 * 128 + wave * 32;
    const int qpb1 = qb1 * 128 + wave * 32;

    const int cg = (t & 7) * 8, rr = t >> 3;
    const bf16* Kbase  = qkv + (long)(b * 2048) * RS + 1024 + h * 64;
    const bf16* Vtbase = Vt + ((long)bh * 64) * 2048;

    bf16x8 kreg[2], vreg[2];
#pragma unroll
    for (int pp = 0; pp < 2; pp++) {   // prefetch tile 0
        kreg[pp] = *(const bf16x8*)(Kbase + (long)(pp * 32 + rr) * RS + cg);
        vreg[pp] = *(const bf16x8*)(Vtbase + (long)(pp * 32 + rr) * 2048 + cg);
    }

    for (int ti = 0; ti < nt1; ti++) {
        __syncthreads();
#pragma unroll
        for (int pp = 0; pp < 2; pp++) {
            *(bf16x8*)(&sK[(pp * 32 + rr) * 72 + cg]) = kreg[pp];
            *(bf16x8*)(&sVt[(pp * 32 + rr) * 72 + cg]) = vreg[pp];
        }
        __syncthreads();
        if (ti + 1 < nt1) {
            int t0n = (ti + 1) * 64;
#pragma unroll
            for (int pp = 0; pp < 2; pp++) {
                kreg[pp] = *(const bf16x8*)(Kbase + (long)(t0n + pp * 32 + rr) * RS + cg);
                vreg[pp] = *(const bf16x8*)(Vtbase + (long)(pp * 32 + rr) * 2048 + t0n + cg);
            }
        }
        const int t0 = ti * 64;

        bf16x8 kf[4][2];
#pragma unroll
        for (int tt = 0; tt < 4; tt++) {
            kf[tt][0] = *(const bf16x8*)(&sK[(tt * 16 + l16) * 72 + quad * 8]);
            kf[tt][1] = *(const bf16x8*)(&sK[(tt * 16 + l16) * 72 + 32 + quad * 8]);
        }
        if (ti < nt0)
            attn_tile(kf, sVt, t0, qpb0, quad, l16, qf[0], o[0], m_i[0], l_i[0]);
        attn_tile(kf, sVt, t0, qpb1, quad, l16, qf[1], o[1], m_i[1], l_i[1]);
    }
#pragma unroll
    for (int s = 0; s < 2; s++) {
        const int qpb = s ? qpb1 : qpb0;
#pragma unroll
        for (int rf = 0; rf < 2; rf++) {
            float rl = 1.0f / l_i[s][rf];
            const long row = (long)(b * 2048 + qpb + rf * 16 + l16) * 1024 + h * 64;
#pragma unroll
            for (int jb = 0; jb < 4; jb++) {
                bf16x4 ov;
#pragma unroll
                for (int r = 0; r < 4; r++) ov[r] = (bf16)CLAMP(o[s][rf][jb][r] * rl);
                *(bf16x4*)(&ctx[row + jb * 16 + quad * 4]) = ov;
            }
        }
    }
}

// ---------------- confidence head (f32) ----------------
__global__ __launch_bounds__(256)
void conf_partial(const float* __restrict__ xout, const float* __restrict__ cw, float* __restrict__ part)
{
    int blk = blockIdx.x;
    int b = blk >> 6, chunk = blk & 63;
    int t = threadIdx.x;
    int d0 = t * 4;
    f32x4 w = *(const f32x4*)(cw + d0);
    float acc = 0.f;
    for (int s = chunk * 32; s < chunk * 32 + 32; s++) {
        f32x4 v = *(const f32x4*)(xout + (long)(b * 2048 + s) * 1024 + d0);
        acc += v[0] * w[0] + v[1] * w[1] + v[2] * w[2] + v[3] * w[3];
    }
#pragma unroll
    for (int off = 32; off; off >>= 1) acc += __shfl_xor(acc, off);
    __shared__ float ls[4];
    if ((t & 63) == 0) ls[t >> 6] = acc;
    __syncthreads();
    if (t == 0) part[blk] = ls[0] + ls[1] + ls[2] + ls[3];
}

__global__ void conf_final(const float* __restrict__ part, const float* __restrict__ cb, float* __restrict__ outp)
{
    if (threadIdx.x == 0) {
        float accb = 0.f;
        for (int b = 0; b < 4; b++) {
            float s = 0.f;
            for (int i = 0; i < 64; i++) s += part[b * 64 + i];
            float z = s / 2048.0f + cb[0];
            accb += 1.0f / (1.0f + expf(-z));
        }
        outp[0] = accb * 0.25f;
    }
}

// ---------------- launch ----------------
// Workspace (1 MB = 1<<20), peak 96 MB + 1 KB, phase-disjoint aliasing:
//  [ 0, 8): WqkvT (ph1-3) -> W1T (ph6+)
//  [ 8,16): WoT (ph1-5)   -> W2T (ph6+)
//  [16,32): h (ph2-3) -> ctx (ph4-5) -> h2 (ph7-9)
//  [32,80): qkv (ph3-4); x1 f32 [32,64) ph5+ (qkv dead)
//  [80,96): Vt (ph3.5-4); a1h [64,96) ph8-9 (qkv tail + Vt dead)
//  [96MB):  part f32[256]
extern "C" void kernel_launch(void* const* d_in, const int* in_sizes, int n_in,
                              void* d_out, int out_size, void* d_ws, size_t ws_size,
                              hipStream_t stream)
{
    const int D = 1024, F = 4096, M = 8192;
    const size_t MB = 1u << 20;
    const float* x     = (const float*)d_in[0];
    const float* Wq    = (const float*)d_in[1];
    const float* Wk    = (const float*)d_in[2];
    const float* Wv    = (const float*)d_in[3];
    const float* Wo    = (const float*)d_in[4];
    const float* ln1w  = (const float*)d_in[5];
    const float* ln1b  = (const float*)d_in[6];
    const float* W1    = (const float*)d_in[7];
    const float* b1    = (const float*)d_in[8];
    const float* W2    = (const float*)d_in[9];
    const float* b2    = (const float*)d_in[10];
    const float* ln2w  = (const float*)d_in[11];
    const float* ln2b  = (const float*)d_in[12];
    const float* confw = (const float*)d_in[13];
    const float* confb = (const float*)d_in[14];
    float* out = (float*)d_out;

    char* ws = (char*)d_ws;
    bf16*  WqkvT = (bf16*)(ws);
    bf16*  WoT   = (bf16*)(ws + 8 * MB);
    bf16*  h     = (bf16*)(ws + 16 * MB);
    bf16*  qkv   = (bf16*)(ws + 32 * MB);
    bf16*  Vt    = (bf16*)(ws + 80 * MB);
    bf16*  ctx   = (bf16*)(ws + 16 * MB);
    float* x1    = (float*)(ws + 32 * MB);
    bf16*  h2    = (bf16*)(ws + 16 * MB);
    bf16*  W1T   = (bf16*)(ws);
    bf16*  W2T   = (bf16*)(ws + 8 * MB);
    bf16*  a1h   = (bf16*)(ws + 64 * MB);
    float* part  = (float*)(ws + 96 * MB);

    dim3 tb(32, 8);
    // ph1: QKV/Wo weight transposes in one launch
    transpose4_kernel<<<dim3(32, 32, 4), tb, 0, stream>>>(Wq, Wk, Wv, Wo, WqkvT, WoT);
    // ph2: LN1
    ln_kernel<<<M, 256, 0, stream>>>(x, ln1w, ln1b, h);
    // ph3: QKV projection (256^2 tile: 384 blocks; Q third pre-scaled by SM_C)
    gemm256<0><<<dim3(12, 32), 512, 0, stream>>>(h, D, WqkvT, D, M, 3 * D, D, nullptr, nullptr, qkv, 3 * D);
    // ph3.5: V transpose
    v_transpose<<<dim3(64, 2, 64), tb, 0, stream>>>(qkv, Vt);
    // ph4: attention (diagonal-paired: 512 uniform blocks, fully co-resident)
    attn_kernel<<<dim3(64, 8), 256, 0, stream>>>(qkv, Vt, ctx);
    // ph5: Wo projection + residual -> x1 f32 (128^2: 512 blocks)
    gemm_bt<2><<<dim3(8, 64), 256, 0, stream>>>(ctx, D, WoT, D, M, D, D, nullptr, x, x1, D);
    // ph6: FFN weight transposes
    transpose_kernel<<<dim3(F / 32, D / 32), tb, 0, stream>>>(W1, W1T, D, F);
    transpose_kernel<<<dim3(D / 32, F / 32), tb, 0, stream>>>(W2, W2T, F, D);
    // ph7: LN2
    ln_kernel<<<M, 256, 0, stream>>>(x1, ln2w, ln2b, h2);
    // ph8: FFN half 1 (inner 256^2: 256 blocks; outer 128^2 k-split accumulate)
    gemm256<1><<<dim3(8, 32), 512, 0, stream>>>(h2, D, W1T, D, M, 2048, D, b1, nullptr, a1h, 2048);
    gemm_bt<4><<<dim3(8, 64), 256, 0, stream>>>(a1h, 2048, W2T, F, M, D, 2048, nullptr, nullptr, x1, D);
    // ph9: FFN half 2 -> out f32
    gemm256<1><<<dim3(8, 32), 512, 0, stream>>>(h2, D, W1T + (size_t)2048 * D, D, M, 2048, D, b1 + 2048, nullptr, a1h, 2048);
    gemm_bt<3><<<dim3(8, 64), 256, 0, stream>>>(a1h, 2048, W2T + 2048, F, M, D, 2048, b2, x1, out, D);
    // ph10: confidence head
    conf_partial<<<256, 256, 0, stream>>>(out, confw, part);
    conf_final<<<1, 64, 0, stream>>>(part, confb, out + (size_t)M * D);
}